// Round 11
// baseline (32593.552 us; speedup 1.0000x reference)
//
#include <hip/hip_runtime.h>
#include <algorithm>

typedef __bf16 bf16;
typedef __bf16 bf16x8 __attribute__((ext_vector_type(8)));
typedef float f32x4 __attribute__((ext_vector_type(4)));
typedef unsigned long long u64;

// SEQ=256, B=128, XD=128, HD=1024, ZD=64
#define SEQ 256
#define BATCH 128
#define XD 128
#define HD 1024
#define ZD 64
#define MROWS (SEQ * BATCH)
#define BH (BATCH * HD)   // 131072
#define B3 (BATCH * 3072) // 393216
#define DYN_LDS 149824
#define NBLK 256

__device__ __forceinline__ f32x4 mfma16(bf16x8 a, bf16x8 b, f32x4 c) {
  return __builtin_amdgcn_mfma_f32_16x16x32_bf16(a, b, c, 0, 0, 0);
}
__device__ __forceinline__ float sigmoidf_(float x) { return 1.f / (1.f + __expf(-x)); }

// ---- access helpers ----------------------------------------------------------------
// 16B load, sc0 only: bypass L1, ALLOCATE in local XCD L2 (same caching class as the
// compiler's relaxed-agent atomic load -> broadcast lines are L2-amplified per XCD).
__device__ __forceinline__ bf16x8 cld16(const bf16* p) {
  bf16x8 v;
  asm volatile("global_load_dwordx4 %0, %1, off sc0" : "=v"(v) : "v"(p));
  return v;
}
__device__ __forceinline__ bf16x8 cld8(const bf16* ptr) {
  u64 a = __hip_atomic_load((const u64*)ptr, __ATOMIC_RELAXED, __HIP_MEMORY_SCOPE_AGENT);
  u64 b = __hip_atomic_load((const u64*)ptr + 1, __ATOMIC_RELAXED, __HIP_MEMORY_SCOPE_AGENT);
  union { u64 u[2]; bf16x8 v; } t;
  t.u[0] = a; t.u[1] = b;
  return t.v;
}
__device__ __forceinline__ float cldf(const float* p) {
  unsigned w = __hip_atomic_load((const unsigned*)p, __ATOMIC_RELAXED, __HIP_MEMORY_SCOPE_AGENT);
  return __builtin_bit_cast(float, w);
}
__device__ __forceinline__ void cstf(float* p, float v) {
  __hip_atomic_store((unsigned*)p, __builtin_bit_cast(unsigned, v), __ATOMIC_RELAXED,
                     __HIP_MEMORY_SCOPE_AGENT);
}
__device__ __forceinline__ float cldbf(const bf16* p) {
  size_t a = (size_t)p;
  unsigned w = __hip_atomic_load((const unsigned*)(a & ~(size_t)3), __ATOMIC_RELAXED,
                                 __HIP_MEMORY_SCOPE_AGENT);
  unsigned short h = (a & 2) ? (unsigned short)(w >> 16) : (unsigned short)(w & 0xffffu);
  return (float)__builtin_bit_cast(bf16, h);
}
__device__ __forceinline__ void cstb(bf16* p, float v) {
  bf16 b = (bf16)v;
  unsigned hv = (unsigned)__builtin_bit_cast(unsigned short, b);
  asm volatile("global_store_short %0, %1, off sc0 sc1" ::"v"(p), "v"(hv));
}
// drain asm loads + fence scheduler so MFMAs can't hoist above (guide rule #18)
__device__ __forceinline__ void vwait() {
  asm volatile("s_waitcnt vmcnt(0)" ::: "memory");
  __builtin_amdgcn_sched_barrier(0);
}

// ---- two-level tree grid barrier (R6-proven, s_sleep poll) -------------------------
__device__ __forceinline__ void gbar(unsigned* arr, unsigned* sum, unsigned serial) {
  asm volatile("s_waitcnt vmcnt(0) lgkmcnt(0)" ::: "memory");
  __syncthreads();
  const int tid = threadIdx.x;
  const int bid = blockIdx.x;
  if (tid == 0)
    __hip_atomic_store(arr + (size_t)bid * 32, serial, __ATOMIC_RELAXED,
                       __HIP_MEMORY_SCOPE_AGENT);
  if ((bid & 15) == 0 && tid < 16) {
    const unsigned* f = arr + (size_t)((bid & ~15) + tid) * 32;
    while (__hip_atomic_load(f, __ATOMIC_RELAXED, __HIP_MEMORY_SCOPE_AGENT) < serial)
      __builtin_amdgcn_s_sleep(2);
  }
  __syncthreads();
  if ((bid & 15) == 0 && tid == 0)
    __hip_atomic_store(sum + (size_t)(bid >> 4) * 32, serial, __ATOMIC_RELAXED,
                       __HIP_MEMORY_SCOPE_AGENT);
  if (tid < 16) {
    const unsigned* f = sum + (size_t)tid * 32;
    while (__hip_atomic_load(f, __ATOMIC_RELAXED, __HIP_MEMORY_SCOPE_AGENT) < serial)
      __builtin_amdgcn_s_sleep(2);
  }
  __builtin_amdgcn_fence(__ATOMIC_ACQUIRE, "workgroup");
  __syncthreads();
}

// ---------- generic mma (global A, global B) for prologue/tail kernels --------------
template <int MT, int NT>
__device__ __forceinline__ void mma_block(const bf16* __restrict__ a0, size_t aStride,
                                          const bf16* __restrict__ b0, size_t bStride,
                                          int K, f32x4 acc[MT][NT]) {
#pragma unroll 2
  for (int k = 0; k < K; k += 32) {
    bf16x8 af[MT], bfr[NT];
#pragma unroll
    for (int i = 0; i < MT; ++i) af[i] = *(const bf16x8*)(a0 + (size_t)i * aStride + k);
#pragma unroll
    for (int j = 0; j < NT; ++j) bfr[j] = *(const bf16x8*)(b0 + (size_t)j * bStride + k);
#pragma unroll
    for (int i = 0; i < MT; ++i)
#pragma unroll
      for (int j = 0; j < NT; ++j) acc[i][j] = mfma16(af[i], bfr[j], acc[i][j]);
  }
}

// ---------------- fp32 -> bf16 conversion (column slicing for concat splits) --------
__global__ void cvt_k(bf16* __restrict__ dst, const float* __restrict__ src, long n,
                      int cols, int src_ld, int col_off) {
  long i = (long)blockIdx.x * blockDim.x + threadIdx.x;
  long stride = (long)gridDim.x * blockDim.x;
  for (; i < n; i += stride) {
    long row = i / cols;
    int c = (int)(i - row * cols);
    dst[i] = (bf16)src[row * (long)src_ld + col_off + c];
  }
}

// ---------------- generic GEMM (B^T) for prologue ----------------------------------
struct Epi {
  bf16* C;
  float* Cf;
  const float* bias;
  const bf16* add;
  int relu;
  int ldc;
};

template <int MT, int NT>
__global__ void gemm_bt(const bf16* __restrict__ A, int lda, const bf16* __restrict__ B,
                        int ldb, int M, int N, int K, Epi e) {
  const int lane = threadIdx.x & 63;
  const int r = lane & 15, kb = lane >> 4;
  const int gw = blockIdx.x * (blockDim.x >> 6) + (threadIdx.x >> 6);
  const int nw = gridDim.x * (blockDim.x >> 6);
  const int ntm = M / (16 * MT), ntn = N / (16 * NT);
  for (int task = gw; task < ntm * ntn; task += nw) {
    int mt = task % ntm, nt = task / ntm;
    int m0 = mt * 16 * MT, n0 = nt * 16 * NT;
    f32x4 acc[MT][NT] = {};
    const bf16* a0 = A + (size_t)(m0 + r) * lda + kb * 8;
    const bf16* b0 = B + (size_t)(n0 + r) * ldb + kb * 8;
    mma_block<MT, NT>(a0, (size_t)16 * lda, b0, (size_t)16 * ldb, K, acc);
#pragma unroll
    for (int i = 0; i < MT; ++i)
#pragma unroll
      for (int j = 0; j < NT; ++j)
#pragma unroll
        for (int q = 0; q < 4; ++q) {
          size_t gm = (size_t)m0 + i * 16 + kb * 4 + q;
          int gn = n0 + j * 16 + r;
          float v = acc[i][j][q] + e.bias[gn];
          if (e.add) v += (float)e.add[gm * e.ldc + gn];
          if (e.relu) v = fmaxf(v, 0.f);
          if (e.Cf) e.Cf[gm * e.ldc + gn] = v;
          else e.C[gm * e.ldc + gn] = (bf16)v;
        }
  }
}

// ===================== the LDS-weight-pinned recurrence ==============================
struct LoopP {
  const bf16 *WA, *WB, *WPZ, *WIZ, *WIX, *WXX, *WPX, *WDZ, *WD2, *XBF;
  bf16 *HB, *PT, *ET, *PHIX, *ENCX, *PHIZ, *DHP, *DECH;
  float *H, *GH, *GIX, *KLD, *RPART, *out;
  unsigned *ARR, *SUM;
  const float *eps, *x;
  const float *prior_b, *gru_bh, *gru_bi, *pm_b, *ps_b, *em_b, *es_b, *pz_b, *phx_b,
      *enc_b, *dec1_b, *dec2_b;
};

// stage 16 rows x K=1024 into k-major LDS unit: [128 kg][16 row][16B]
__device__ __forceinline__ void stage1024(char* lds, int off, const bf16* src) {
  for (int c = threadIdx.x; c < 2048; c += 512) {
    int kg = c & 127, rr = c >> 7;
    *(float4*)(lds + off + (((kg << 4) + rr) << 4)) =
        *(const float4*)(src + (size_t)rr * 1024 + kg * 8);
  }
}

template <int KK>
__device__ __forceinline__ void load_af(bf16x8* af, const bf16* A, int row, int lda, int k0,
                                        int kb) {
#pragma unroll
  for (int kk = 0; kk < KK; ++kk)
    af[kk] = *(const bf16x8*)(A + (size_t)row * lda + k0 + kk * 32 + kb * 8);
}

// NU weight units (32KB slabs); A-row prefetched in full (32 x 16B sc0 loads)
template <int NU>
__device__ __forceinline__ void run_units(const bf16* Arow, const char* slab0, f32x4* acc,
                                          int r, int kb) {
  bf16x8 af[32];
#pragma unroll
  for (int kk = 0; kk < 32; ++kk) af[kk] = cld16(Arow + kk * 32 + kb * 8);
  vwait();
#pragma unroll
  for (int u = 0; u < NU; ++u)
#pragma unroll
    for (int kk = 0; kk < 32; ++kk)
      acc[u] = mfma16(af[kk],
                      *(const bf16x8*)(slab0 + u * 32768 + ((((kk * 4 + kb) << 4) + r) << 4)),
                      acc[u]);
}

// Block classes: 0 special(0-7), 1 hb(8-103,P), 2 dec1(104-119,P), 3 phix(120-121,P),
//                4 encx/gix(122-185,Q), 5 dec2(186-187,Q), 6 giz(188-251,R), 7 idle
__global__ void __launch_bounds__(512, 2) vrnn_loop(LoopP p) {
  extern __shared__ char lds[];
  const int tid = threadIdx.x, lane = tid & 63, wv = tid >> 6;
  const int r = lane & 15, kb = lane >> 4;
  const int b = blockIdx.x;
  unsigned bs = 0;

  int cls, uid0 = 0, gizj = 0, wpxb = 0;
  if (b < 8) cls = 0;
  else if (b < 104) { cls = 1; uid0 = 4 * (b - 8); }
  else if (b < 120) { cls = 2; uid0 = 4 * (b - 104); }
  else if (b < 122) { cls = 3; wpxb = b - 120; }
  else if (b < 186) { cls = 4; uid0 = 4 * (b - 122); }
  else if (b < 188) { cls = 5; uid0 = 4 * (b - 186); }
  else if (b < 252) { cls = 6; gizj = b - 188; }
  else cls = 7;

  // ----- one-time LDS weight staging -----
  if (cls == 0) {
    for (int c = tid; c < 8192; c += 512) { // WPZ: 64 units of 2KB (K=64)
      int kg = c & 7, rr = (c >> 3) & 15, u = c >> 7;
      *(float4*)(lds + u * 2048 + (((kg << 4) + rr) << 4)) =
          *(const float4*)(p.WPZ + (size_t)(u * 16 + rr) * 64 + kg * 8);
    }
  } else if (cls == 1) {
    for (int u = 0; u < 4; ++u) stage1024(lds, u * 32768, p.WA + (size_t)(uid0 + u) * 16 * 1024);
  } else if (cls == 2) {
    for (int u = 0; u < 4; ++u) stage1024(lds, u * 32768, p.WDZ + (size_t)(uid0 + u) * 16 * 1024);
  } else if (cls == 3) {
    for (int c = tid; c < 8192; c += 512) { // 32 WPX units of 4KB (K=128)
      int u = c >> 8, kg = c & 15, rr = (c >> 4) & 15;
      *(float4*)(lds + u * 4096 + (((kg << 4) + rr) << 4)) =
          *(const float4*)(p.WPX + (size_t)((wpxb * 32 + u) * 16 + rr) * 128 + kg * 8);
    }
  } else if (cls == 4) {
    for (int u = 0; u < 4; ++u) {
      int uid = uid0 + u;
      const bf16* src = (uid < 64) ? p.WXX + (size_t)uid * 16 * 1024
                                   : p.WIX + (size_t)(uid - 64) * 16 * 1024;
      stage1024(lds, u * 32768, src);
    }
  } else if (cls == 5) {
    for (int u = 0; u < 4; ++u) stage1024(lds, u * 32768, p.WD2 + (size_t)(uid0 + u) * 16 * 1024);
  } else if (cls == 6) {
    for (int g = 0; g < 3; ++g)
      stage1024(lds, g * 32768, p.WIZ + (size_t)(g * 1024 + gizj * 16) * 1024);
  }
  __syncthreads();

  for (int t = 0; t < SEQ; ++t) {
    const int cur = t & 1, oth = cur ^ 1;

    // ================= Phase P =================
    if (cls == 1) { // [prior|ench|gh|dhp] = h @ WA
      const bf16* Arow = p.HB + (size_t)(wv * 16 + r) * HD;
      f32x4 acc[4] = {};
      run_units<4>(Arow, lds, acc, r, kb);
      for (int u = 0; u < 4; ++u) {
        int uid = uid0 + u, gn = uid * 16 + r;
#pragma unroll
        for (int qq = 0; qq < 4; ++qq) {
          int gm = wv * 16 + kb * 4 + qq;
          float v = acc[u][qq];
          if (uid < 64) {
            cstb(&p.PT[gm * HD + gn], fmaxf(v + p.prior_b[gn], 0.f));
          } else if (uid < 128) {
            int c = gn - 1024;
            float ex = cldbf(&p.ENCX[(size_t)cur * BH + gm * HD + c]);
            cstb(&p.ET[gm * HD + c], fmaxf(v + ex, 0.f));
          } else if (uid < 320) {
            int c = gn - 2048;
            cstf(&p.GH[gm * 3072 + c], v + p.gru_bh[c]);
          } else {
            int c = gn - 5120;
            cstb(&p.DHP[(size_t)cur * BH + gm * HD + c], v);
          }
        }
      }
    } else if (cls == 2 && t > 0) { // dec1_{t-1} = relu(phiz@WDZ + dhp + b)
      const bf16* Arow = p.PHIZ + (size_t)oth * BH + (size_t)(wv * 16 + r) * HD;
      f32x4 acc[4] = {};
      run_units<4>(Arow, lds, acc, r, kb);
      for (int u = 0; u < 4; ++u) {
        int c = (uid0 + u) * 16 + r;
#pragma unroll
        for (int qq = 0; qq < 4; ++qq) {
          int gm = wv * 16 + kb * 4 + qq;
          float dh = cldbf(&p.DHP[(size_t)oth * BH + gm * HD + c]);
          cstb(&p.DECH[gm * HD + c], fmaxf(acc[u][qq] + dh + p.dec1_b[c], 0.f));
        }
      }
    } else if (cls == 3 && t < SEQ - 1) { // phi_x_{t+1}, K=128, 32 units
      bf16x8 af2[4];
      load_af<4>(af2, p.XBF + (size_t)(t + 1) * BATCH * XD, wv * 16 + r, 128, 0, kb);
      for (int u = 0; u < 32; ++u) {
        f32x4 acc = {};
#pragma unroll
        for (int kk = 0; kk < 4; ++kk)
          acc = mfma16(af2[kk],
                       *(const bf16x8*)(lds + u * 4096 + ((((kk * 4 + kb) << 4) + r) << 4)),
                       acc);
        int gn = (wpxb * 32 + u) * 16 + r;
#pragma unroll
        for (int qq = 0; qq < 4; ++qq) {
          int gm = wv * 16 + kb * 4 + qq;
          cstb(&p.PHIX[gm * HD + gn], fmaxf(acc[qq] + p.phx_b[gn], 0.f));
        }
      }
    }
    gbar(p.ARR, p.SUM, ++bs);

    // ================= Phase Q =================
    if (cls == 0) { // meanstd -> z/kld -> phiz
      const int m0 = b * 16;
      const int mat = wv & 3, half = wv >> 2;
      float* sm = (float*)(lds + 131072);
      bf16* zs = (bf16*)(lds + 147456);
      float* red = (float*)(lds + 149760);
      {
        const bf16* Arow = ((mat < 2) ? p.PT : p.ET) + (size_t)(m0 + r) * HD;
        bf16x8 af[32];
#pragma unroll
        for (int kk = 0; kk < 32; ++kk) af[kk] = cld16(Arow + kk * 32 + kb * 8);
        vwait();
        const float* bw = mat == 0 ? p.pm_b : mat == 1 ? p.ps_b : mat == 2 ? p.em_b : p.es_b;
#pragma unroll 1
        for (int nt = 0; nt < 2; ++nt) {
          int colb = half * 32 + nt * 16;
          f32x4 acc = {};
#pragma unroll
          for (int kk = 0; kk < 32; ++kk)
            acc = mfma16(af[kk],
                         *(const bf16x8*)(p.WB + (size_t)(mat * 64 + colb + r) * 1024 +
                                          kk * 32 + kb * 8),
                         acc);
#pragma unroll
          for (int qq = 0; qq < 4; ++qq)
            sm[mat * 1024 + (kb * 4 + qq) * 64 + colb + r] = acc[qq] + bw[colb + r];
        }
      }
      __syncthreads();
      float kacc = 0.f;
      for (int e = tid; e < 1024; e += 512) {
        int row = e >> 6, col = e & 63;
        float pm = sm[row * 64 + col], ps = sm[1024 + row * 64 + col];
        float em = sm[2048 + row * 64 + col], es = sm[3072 + row * 64 + col];
        float ev = p.eps[((size_t)t * BATCH + m0 + row) * ZD + col];
        zs[row * 72 + col] = (bf16)(em + ev * __expf(0.5f * es));
        float dm = em - pm;
        kacc += 1.f + es - dm * dm - __expf(es - ps);
      }
#pragma unroll
      for (int off = 32; off; off >>= 1) kacc += __shfl_down(kacc, off, 64);
      if (lane == 0) red[wv] = kacc;
      __syncthreads();
      if (tid == 0) {
        float ss = 0.f;
        for (int i = 0; i < 8; ++i) ss += red[i];
        p.KLD[t * 8 + b] = ss;
      }
      bf16x8 afz[2];
      afz[0] = *(const bf16x8*)(zs + r * 72 + kb * 8);
      afz[1] = *(const bf16x8*)(zs + r * 72 + 32 + kb * 8);
#pragma unroll 1
      for (int j = 0; j < 8; ++j) {
        int u = wv * 8 + j;
        f32x4 acc = {};
#pragma unroll
        for (int kk = 0; kk < 2; ++kk)
          acc = mfma16(afz[kk],
                       *(const bf16x8*)(lds + u * 2048 + ((((kk * 4 + kb) << 4) + r) << 4)),
                       acc);
        int gn = u * 16 + r;
#pragma unroll
        for (int qq = 0; qq < 4; ++qq) {
          int gm = m0 + kb * 4 + qq;
          cstb(&p.PHIZ[(size_t)cur * BH + gm * HD + gn], fmaxf(acc[qq] + p.pz_b[gn], 0.f));
        }
      }
    } else if (cls == 4 && t < SEQ - 1) { // [encx|gix]_{t+1} = phix @ [WXX|WIX]
      const bf16* Arow = p.PHIX + (size_t)(wv * 16 + r) * HD;
      f32x4 acc[4] = {};
      run_units<4>(Arow, lds, acc, r, kb);
      for (int u = 0; u < 4; ++u) {
        int uid = uid0 + u;
#pragma unroll
        for (int qq = 0; qq < 4; ++qq) {
          int gm = wv * 16 + kb * 4 + qq;
          if (uid < 64) {
            int c = uid * 16 + r;
            cstb(&p.ENCX[(size_t)oth * BH + gm * HD + c], acc[u][qq] + p.enc_b[c]);
          } else {
            int c = (uid - 64) * 16 + r;
            cstf(&p.GIX[(size_t)oth * B3 + gm * 3072 + c], acc[u][qq] + p.gru_bi[c]);
          }
        }
      }
    } else if (cls == 5 && t > 0) { // dec2_{t-1} + recon + sigmoid
      const bf16* Arow = p.DECH + (size_t)(wv * 16 + r) * HD;
      f32x4 acc[4] = {};
      run_units<4>(Arow, lds, acc, r, kb);
      float racc = 0.f;
      for (int u = 0; u < 4; ++u) {
        int c = (uid0 + u) * 16 + r;
#pragma unroll
        for (int qq = 0; qq < 4; ++qq) {
          int gm = wv * 16 + kb * 4 + qq;
          float l = acc[u][qq] + p.dec2_b[c];
          size_t oi = ((size_t)(t - 1) * BATCH + gm) * XD + c;
          p.out[2 + oi] = sigmoidf_(l);
          float spp = fmaxf(l, 0.f) + log1pf(__expf(-fabsf(l)));
          racc += spp - p.x[oi] * l;
        }
      }
#pragma unroll
      for (int off = 32; off; off >>= 1) racc += __shfl_down(racc, off, 64);
      if (lane == 0) p.RPART[(t - 1) * 64 + uid0 * 2 + wv] = racc;
    }
    gbar(p.ARR, p.SUM, ++bs);

    // ================= Phase R: fused giz + GRU (K-split across wave halves) =========
    if (cls == 6) {
      const int khalf = wv >> 2;
      float* sc = (float*)(lds + 98304); // [4][3][256]
#pragma unroll 1
      for (int pass = 0; pass < 2; ++pass) {
        int mt = (wv & 3) + 4 * pass;
        const bf16* Arow = p.PHIZ + (size_t)cur * BH + (size_t)(mt * 16 + r) * HD;
        bf16x8 af[16];
#pragma unroll
        for (int kk = 0; kk < 16; ++kk)
          af[kk] = cld16(Arow + khalf * 512 + kk * 32 + kb * 8);
        vwait();
        f32x4 a3[3] = {};
#pragma unroll
        for (int kk = 0; kk < 16; ++kk) {
          bf16x8 a = af[kk];
#pragma unroll
          for (int g = 0; g < 3; ++g)
            a3[g] = mfma16(a,
                           *(const bf16x8*)(lds + g * 32768 +
                                            (((((khalf * 16 + kk) * 4 + kb) << 4) + r) << 4)),
                           a3[g]);
        }
        if (khalf) {
#pragma unroll
          for (int g = 0; g < 3; ++g)
#pragma unroll
            for (int qq = 0; qq < 4; ++qq)
              sc[((wv & 3) * 3 + g) * 256 + (kb * 4 + qq) * 16 + r] = a3[g][qq];
        }
        __syncthreads();
        if (!khalf) {
          int c = gizj * 16 + r;
#pragma unroll
          for (int qq = 0; qq < 4; ++qq) {
            int gm = mt * 16 + kb * 4 + qq;
            int si = (kb * 4 + qq) * 16 + r;
            float ir = a3[0][qq] + sc[((wv & 3) * 3 + 0) * 256 + si] +
                       cldf(&p.GIX[(size_t)cur * B3 + gm * 3072 + c]);
            float iz = a3[1][qq] + sc[((wv & 3) * 3 + 1) * 256 + si] +
                       cldf(&p.GIX[(size_t)cur * B3 + gm * 3072 + c + 1024]);
            float in_ = a3[2][qq] + sc[((wv & 3) * 3 + 2) * 256 + si] +
                        cldf(&p.GIX[(size_t)cur * B3 + gm * 3072 + c + 2048]);
            float hr = cldf(&p.GH[gm * 3072 + c]);
            float hz = cldf(&p.GH[gm * 3072 + c + 1024]);
            float hn = cldf(&p.GH[gm * 3072 + c + 2048]);
            float rr2 = sigmoidf_(ir + hr), zg = sigmoidf_(iz + hz);
            float nn = tanhf(in_ + rr2 * hn);
            float hv = p.H[gm * HD + c]; // block-private
            float hnew = (1.f - zg) * nn + zg * hv;
            p.H[gm * HD + c] = hnew;
            cstb(&p.HB[gm * HD + c], hnew);
          }
        }
        __syncthreads();
      }
    }
    gbar(p.ARR, p.SUM, ++bs);
  }
}

// ---------------- epilogue dec2 for t=255 -------------------------------------------
__global__ void dec2_last(const bf16* __restrict__ A, const bf16* __restrict__ W,
                          const float* __restrict__ x, const float* __restrict__ b2,
                          float* __restrict__ out, float* __restrict__ rpart) {
  const int lane = threadIdx.x & 63;
  const int r = lane & 15, kb = lane >> 4;
  const int w = blockIdx.x * 4 + (threadIdx.x >> 6); // 0..63
  const int m0 = (w & 7) * 16, n0 = (w >> 3) * 16;
  f32x4 acc[1][1] = {};
  const bf16* a0 = A + (size_t)(m0 + r) * HD + kb * 8;
  const bf16* b0 = W + (size_t)(n0 + r) * HD + kb * 8;
  mma_block<1, 1>(a0, 0, b0, (size_t)16 * HD, HD, acc);
  float racc = 0.f;
#pragma unroll
  for (int q = 0; q < 4; ++q) {
    int gm = m0 + kb * 4 + q, gn = n0 + r;
    float l = acc[0][0][q] + b2[gn];
    size_t oi = ((size_t)255 * BATCH + gm) * XD + gn;
    out[2 + oi] = sigmoidf_(l);
    float spp = fmaxf(l, 0.f) + log1pf(__expf(-fabsf(l)));
    racc += spp - x[oi] * l;
  }
#pragma unroll
  for (int off = 32; off; off >>= 1) racc += __shfl_down(racc, off, 64);
  if (lane == 0) rpart[255 * 64 + w] = racc;
}

__global__ void finalize_k(const float* __restrict__ rp, const float* __restrict__ kp,
                           float* __restrict__ out) {
  __shared__ float s[256];
  int tid = threadIdx.x;
  float a = 0.f;
  for (int i = tid; i < 256 * 64; i += 256) a += rp[i];
  s[tid] = a;
  __syncthreads();
  for (int off = 128; off > 0; off >>= 1) {
    if (tid < off) s[tid] += s[tid + off];
    __syncthreads();
  }
  if (tid == 0) out[0] = s[0] / (float)BATCH;
  __syncthreads();
  float bb = 0.f;
  for (int i = tid; i < 2048; i += 256) bb += kp[i];
  s[tid] = bb;
  __syncthreads();
  for (int off = 128; off > 0; off >>= 1) {
    if (tid < off) s[tid] += s[tid + off];
    __syncthreads();
  }
  if (tid == 0) out[1] = -0.5f * s[0] / (float)BATCH;
}

__global__ void sentinel_k(float* out) {
  if (threadIdx.x == 0) { out[0] = 1e9f; out[1] = 1e9f; }
}

// =====================================================================================
extern "C" void kernel_launch(void* const* d_in, const int* in_sizes, int n_in, void* d_out,
                              int out_size, void* d_ws, size_t ws_size, hipStream_t stream) {
  const float* x = (const float*)d_in[0];
  const float* eps = (const float*)d_in[1];
  const float* phi_x_W = (const float*)d_in[2];
  const float* phi_x_b = (const float*)d_in[3];
  const float* enc_W = (const float*)d_in[4];
  const float* enc_b = (const float*)d_in[5];
  const float* enc_mean_W = (const float*)d_in[6];
  const float* enc_mean_b = (const float*)d_in[7];
  const float* enc_std_W = (const float*)d_in[8];
  const float* enc_std_b = (const float*)d_in[9];
  const float* prior_W = (const float*)d_in[10];
  const float* prior_b = (const float*)d_in[11];
  const float* prior_mean_W = (const float*)d_in[12];
  const float* prior_mean_b = (const float*)d_in[13];
  const float* prior_std_W = (const float*)d_in[14];
  const float* prior_std_b = (const float*)d_in[15];
  const float* phi_z_W = (const float*)d_in[16];
  const float* phi_z_b = (const float*)d_in[17];
  const float* dec1_W = (const float*)d_in[18];
  const float* dec1_b = (const float*)d_in[19];
  const float* dec2_W = (const float*)d_in[20];
  const float* dec2_b = (const float*)d_in[21];
  const float* gru_Wi = (const float*)d_in[22];
  const float* gru_Wh = (const float*)d_in[23];
  const float* gru_bi = (const float*)d_in[24];
  const float* gru_bh = (const float*)d_in[25];
  float* out = (float*)d_out;

  char* w = (char*)d_ws;
  auto carve = [&](size_t bytes) {
    char* pp = w;
    w += (bytes + 255) & ~(size_t)255;
    return pp;
  };
  bf16* WA = (bf16*)carve((size_t)6144 * HD * 2);  // [prior;ench;gh;dhp]
  bf16* WB = (bf16*)carve((size_t)256 * HD * 2);   // [pm;ps;em;es]
  bf16* WPZ = (bf16*)carve((size_t)HD * ZD * 2);
  bf16* WIZ = (bf16*)carve((size_t)3072 * HD * 2); // gru_Wi[:,1024:]
  bf16* WIX = (bf16*)carve((size_t)3072 * HD * 2); // gru_Wi[:,:1024]
  bf16* WXX = (bf16*)carve((size_t)HD * HD * 2);   // enc_W[:,:1024]
  bf16* WPX = (bf16*)carve((size_t)HD * XD * 2);
  bf16* WDZ = (bf16*)carve((size_t)HD * HD * 2);   // dec1_W[:,:1024]
  bf16* WD2 = (bf16*)carve((size_t)XD * HD * 2);
  bf16* XBF = (bf16*)carve((size_t)MROWS * XD * 2);
  float* H = (float*)carve((size_t)BH * 4);
  bf16* HB = (bf16*)carve((size_t)BH * 2);
  bf16* PT = (bf16*)carve((size_t)BH * 2);
  bf16* ET = (bf16*)carve((size_t)BH * 2);
  float* GH = (float*)carve((size_t)B3 * 4);
  bf16* PHIX = (bf16*)carve((size_t)BH * 2);
  bf16* ENCX = (bf16*)carve((size_t)2 * BH * 2);
  bf16* PHIZ = (bf16*)carve((size_t)2 * BH * 2);
  bf16* DHP = (bf16*)carve((size_t)2 * BH * 2);
  bf16* DECH = (bf16*)carve((size_t)BH * 2);
  float* GIX = (float*)carve((size_t)2 * B3 * 4);
  float* KLD = (float*)carve((size_t)SEQ * 8 * 4);
  float* RPART = (float*)carve((size_t)SEQ * 64 * 4);
  unsigned* ARR = (unsigned*)carve((size_t)NBLK * 32 * 4);
  unsigned* SUM = (unsigned*)carve((size_t)16 * 32 * 4);
  if ((size_t)(w - (char*)d_ws) > ws_size) {
    sentinel_k<<<1, 64, 0, stream>>>(out);
    return;
  }

  auto cvt = [&](bf16* dst, const float* src, long n, int cols, int ld, int off) {
    int grid = (int)std::min((n + 255) / 256, (long)2048);
    cvt_k<<<grid, 256, 0, stream>>>(dst, src, n, cols, ld, off);
  };
  cvt(WA, prior_W, (long)HD * HD, HD, HD, 0);
  cvt(WA + (size_t)HD * HD, enc_W, (long)HD * HD, HD, 2 * HD, HD);
  cvt(WA + (size_t)2048 * HD, gru_Wh, (long)3072 * HD, HD, HD, 0);
  cvt(WA + (size_t)5120 * HD, dec1_W, (long)HD * HD, HD, 2 * HD, HD);
  cvt(WB, prior_mean_W, (long)ZD * HD, HD, HD, 0);
  cvt(WB + (size_t)64 * HD, prior_std_W, (long)ZD * HD, HD, HD, 0);
  cvt(WB + (size_t)128 * HD, enc_mean_W, (long)ZD * HD, HD, HD, 0);
  cvt(WB + (size_t)192 * HD, enc_std_W, (long)ZD * HD, HD, HD, 0);
  cvt(WPZ, phi_z_W, (long)HD * ZD, ZD, ZD, 0);
  cvt(WIZ, gru_Wi, (long)3072 * HD, HD, 2 * HD, HD);
  cvt(WIX, gru_Wi, (long)3072 * HD, HD, 2 * HD, 0);
  cvt(WXX, enc_W, (long)HD * HD, HD, 2 * HD, 0);
  cvt(WPX, phi_x_W, (long)HD * XD, XD, XD, 0);
  cvt(WDZ, dec1_W, (long)HD * HD, HD, 2 * HD, 0);
  cvt(WD2, dec2_W, (long)XD * HD, HD, HD, 0);
  cvt(XBF, x, (long)MROWS * XD, XD, XD, 0);

  hipMemsetAsync(H, 0, (size_t)BH * 4, stream);
  hipMemsetAsync(HB, 0, (size_t)BH * 2, stream);
  hipMemsetAsync(RPART, 0, (size_t)SEQ * 64 * 4, stream);
  hipMemsetAsync(ARR, 0, (size_t)NBLK * 32 * 4, stream);
  hipMemsetAsync(SUM, 0, (size_t)16 * 32 * 4, stream);

  // prologue: phi_x_0 -> encx_0, gix_0 (slot 0)
  Epi e1{PHIX, nullptr, phi_x_b, nullptr, 1, HD};
  gemm_bt<2, 2><<<32, 256, 0, stream>>>(XBF, XD, WPX, XD, BATCH, HD, XD, e1);
  Epi e2{ENCX, nullptr, enc_b, nullptr, 0, HD};
  gemm_bt<2, 2><<<32, 256, 0, stream>>>(PHIX, HD, WXX, HD, BATCH, HD, HD, e2);
  Epi e3{nullptr, GIX, gru_bi, nullptr, 0, 3072};
  gemm_bt<2, 2><<<96, 256, 0, stream>>>(PHIX, HD, WIX, HD, BATCH, 3072, HD, e3);

  LoopP lp;
  lp.WA = WA; lp.WB = WB; lp.WPZ = WPZ; lp.WIZ = WIZ; lp.WIX = WIX; lp.WXX = WXX;
  lp.WPX = WPX; lp.WDZ = WDZ; lp.WD2 = WD2; lp.XBF = XBF;
  lp.HB = HB; lp.PT = PT; lp.ET = ET; lp.PHIX = PHIX; lp.ENCX = ENCX; lp.PHIZ = PHIZ;
  lp.DHP = DHP; lp.DECH = DECH;
  lp.H = H; lp.GH = GH; lp.GIX = GIX; lp.KLD = KLD; lp.RPART = RPART; lp.out = out;
  lp.ARR = ARR; lp.SUM = SUM;
  lp.eps = eps; lp.x = x;
  lp.prior_b = prior_b; lp.gru_bh = gru_bh; lp.gru_bi = gru_bi;
  lp.pm_b = prior_mean_b; lp.ps_b = prior_std_b; lp.em_b = enc_mean_b; lp.es_b = enc_std_b;
  lp.pz_b = phi_z_b; lp.phx_b = phi_x_b; lp.enc_b = enc_b; lp.dec1_b = dec1_b;
  lp.dec2_b = dec2_b;

  hipFuncSetAttribute(reinterpret_cast<const void*>(vrnn_loop),
                      hipFuncAttributeMaxDynamicSharedMemorySize, DYN_LDS);
  void* args[] = {&lp};
  hipLaunchCooperativeKernel(reinterpret_cast<const void*>(vrnn_loop), dim3(NBLK), dim3(512),
                             args, DYN_LDS, stream);

  // epilogue: dec1_255 (slot 1), dec2_255, losses
  Epi e4{DECH, nullptr, dec1_b, DHP + (size_t)1 * BH, 1, HD};
  gemm_bt<2, 2><<<32, 256, 0, stream>>>(PHIZ + (size_t)1 * BH, HD, WDZ, HD, BATCH, HD, HD, e4);
  dec2_last<<<16, 256, 0, stream>>>(DECH, WD2, x, dec2_b, out, RPART);
  finalize_k<<<1, 256, 0, stream>>>(RPART, KLD, out);
}

// Round 12
// 23988.954 us; speedup vs baseline: 1.3587x; 1.3587x over previous
//
#include <hip/hip_runtime.h>
#include <algorithm>

typedef __bf16 bf16;
typedef __bf16 bf16x8 __attribute__((ext_vector_type(8)));
typedef float f32x4 __attribute__((ext_vector_type(4)));
typedef unsigned long long u64;

// SEQ=256, B=128, XD=128, HD=1024, ZD=64
#define SEQ 256
#define BATCH 128
#define XD 128
#define HD 1024
#define ZD 64
#define MROWS (SEQ * BATCH)
#define BH (BATCH * HD)   // 131072
#define B3 (BATCH * 3072) // 393216
#define DYN_LDS 149824
#define NBLK 256

__device__ __forceinline__ f32x4 mfma16(bf16x8 a, bf16x8 b, f32x4 c) {
  return __builtin_amdgcn_mfma_f32_16x16x32_bf16(a, b, c, 0, 0, 0);
}
__device__ __forceinline__ float sigmoidf_(float x) { return 1.f / (1.f + __expf(-x)); }

// ---- 16B write-through stores (cross-block visible; proven semantics) --------------
__device__ __forceinline__ void cst16(bf16* p, bf16x8 v) {
  asm volatile("global_store_dwordx4 %0, %1, off sc0 sc1" ::"v"(p), "v"(v) : "memory");
}
__device__ __forceinline__ void cst16f(float* p, f32x4 v) {
  asm volatile("global_store_dwordx4 %0, %1, off sc0 sc1" ::"v"(p), "v"(v) : "memory");
}

// ---- two-level tree grid barrier; agent-scope acquire fence (invalidate caches) ----
__device__ __forceinline__ void gbar(unsigned* arr, unsigned* sum, unsigned serial) {
  asm volatile("s_waitcnt vmcnt(0) lgkmcnt(0)" ::: "memory");
  __syncthreads();
  const int tid = threadIdx.x;
  const int bid = blockIdx.x;
  if (tid == 0)
    __hip_atomic_store(arr + (size_t)bid * 32, serial, __ATOMIC_RELAXED,
                       __HIP_MEMORY_SCOPE_AGENT);
  if ((bid & 15) == 0 && tid < 16) {
    const unsigned* f = arr + (size_t)((bid & ~15) + tid) * 32;
    while (__hip_atomic_load(f, __ATOMIC_RELAXED, __HIP_MEMORY_SCOPE_AGENT) < serial)
      __builtin_amdgcn_s_sleep(2);
  }
  __syncthreads();
  if ((bid & 15) == 0 && tid == 0)
    __hip_atomic_store(sum + (size_t)(bid >> 4) * 32, serial, __ATOMIC_RELAXED,
                       __HIP_MEMORY_SCOPE_AGENT);
  if (tid < 16) {
    const unsigned* f = sum + (size_t)tid * 32;
    while (__hip_atomic_load(f, __ATOMIC_RELAXED, __HIP_MEMORY_SCOPE_AGENT) < serial)
      __builtin_amdgcn_s_sleep(2);
  }
  __builtin_amdgcn_fence(__ATOMIC_ACQUIRE, "agent"); // invalidate L1/L2: plain loads OK
  __syncthreads();
}

// ---------- generic mma (global A, global B) for prologue/tail kernels --------------
template <int MT, int NT>
__device__ __forceinline__ void mma_block(const bf16* __restrict__ a0, size_t aStride,
                                          const bf16* __restrict__ b0, size_t bStride,
                                          int K, f32x4 acc[MT][NT]) {
#pragma unroll 2
  for (int k = 0; k < K; k += 32) {
    bf16x8 af[MT], bfr[NT];
#pragma unroll
    for (int i = 0; i < MT; ++i) af[i] = *(const bf16x8*)(a0 + (size_t)i * aStride + k);
#pragma unroll
    for (int j = 0; j < NT; ++j) bfr[j] = *(const bf16x8*)(b0 + (size_t)j * bStride + k);
#pragma unroll
    for (int i = 0; i < MT; ++i)
#pragma unroll
      for (int j = 0; j < NT; ++j) acc[i][j] = mfma16(af[i], bfr[j], acc[i][j]);
  }
}

// ---------------- fp32 -> bf16 conversion (column slicing for concat splits) --------
__global__ void cvt_k(bf16* __restrict__ dst, const float* __restrict__ src, long n,
                      int cols, int src_ld, int col_off) {
  long i = (long)blockIdx.x * blockDim.x + threadIdx.x;
  long stride = (long)gridDim.x * blockDim.x;
  for (; i < n; i += stride) {
    long row = i / cols;
    int c = (int)(i - row * cols);
    dst[i] = (bf16)src[row * (long)src_ld + col_off + c];
  }
}

// ---------------- generic GEMM (B^T) for prologue ----------------------------------
struct Epi {
  bf16* C;
  float* Cf;
  const float* bias;
  const bf16* add;
  int relu;
  int ldc;
};

template <int MT, int NT>
__global__ void gemm_bt(const bf16* __restrict__ A, int lda, const bf16* __restrict__ B,
                        int ldb, int M, int N, int K, Epi e) {
  const int lane = threadIdx.x & 63;
  const int r = lane & 15, kb = lane >> 4;
  const int gw = blockIdx.x * (blockDim.x >> 6) + (threadIdx.x >> 6);
  const int nw = gridDim.x * (blockDim.x >> 6);
  const int ntm = M / (16 * MT), ntn = N / (16 * NT);
  for (int task = gw; task < ntm * ntn; task += nw) {
    int mt = task % ntm, nt = task / ntm;
    int m0 = mt * 16 * MT, n0 = nt * 16 * NT;
    f32x4 acc[MT][NT] = {};
    const bf16* a0 = A + (size_t)(m0 + r) * lda + kb * 8;
    const bf16* b0 = B + (size_t)(n0 + r) * ldb + kb * 8;
    mma_block<MT, NT>(a0, (size_t)16 * lda, b0, (size_t)16 * ldb, K, acc);
#pragma unroll
    for (int i = 0; i < MT; ++i)
#pragma unroll
      for (int j = 0; j < NT; ++j)
#pragma unroll
        for (int q = 0; q < 4; ++q) {
          size_t gm = (size_t)m0 + i * 16 + kb * 4 + q;
          int gn = n0 + j * 16 + r;
          float v = acc[i][j][q] + e.bias[gn];
          if (e.add) v += (float)e.add[gm * e.ldc + gn];
          if (e.relu) v = fmaxf(v, 0.f);
          if (e.Cf) e.Cf[gm * e.ldc + gn] = v;
          else e.C[gm * e.ldc + gn] = (bf16)v;
        }
  }
}

// ===================== the LDS-weight-pinned recurrence ==============================
struct LoopP {
  const bf16 *WA, *WB, *WPZ, *WIZ, *WIX, *WXX, *WPX, *WDZ, *WD2, *XBF;
  bf16 *HB, *PT, *ET, *PHIX, *ENCX, *PHIZ, *DHP, *DECH;
  float *H, *GH, *GIX, *KLD, *RPART, *out;
  unsigned *ARR, *SUM;
  const float *eps, *x;
  const float *prior_b, *gru_bh, *gru_bi, *pm_b, *ps_b, *em_b, *es_b, *pz_b, *phx_b,
      *enc_b, *dec1_b, *dec2_b;
};

// stage 16 rows x K=1024 into k-major LDS unit: [128 kg][16 row][16B]
__device__ __forceinline__ void stage1024(char* lds, int off, const bf16* src) {
  for (int c = threadIdx.x; c < 2048; c += 512) {
    int kg = c & 127, rr = c >> 7;
    *(float4*)(lds + off + (((kg << 4) + rr) << 4)) =
        *(const float4*)(src + (size_t)rr * 1024 + kg * 8);
  }
}

template <int KK>
__device__ __forceinline__ void load_af(bf16x8* af, const bf16* A, int row, int lda, int k0,
                                        int kb) {
#pragma unroll
  for (int kk = 0; kk < KK; ++kk)
    af[kk] = *(const bf16x8*)(A + (size_t)row * lda + k0 + kk * 32 + kb * 8);
}

// NU weight units (32KB slabs); A-row via plain cached 16B loads (L1-coalesced)
template <int NU>
__device__ __forceinline__ void run_units(const bf16* Arow, const char* slab0, f32x4* acc,
                                          int r, int kb) {
  bf16x8 af[32];
#pragma unroll
  for (int kk = 0; kk < 32; ++kk) af[kk] = *(const bf16x8*)(Arow + kk * 32 + kb * 8);
#pragma unroll
  for (int u = 0; u < NU; ++u)
#pragma unroll
    for (int kk = 0; kk < 32; ++kk)
      acc[u] = mfma16(af[kk],
                      *(const bf16x8*)(slab0 + u * 32768 + ((((kk * 4 + kb) << 4) + r) << 4)),
                      acc[u]);
}

// transpose TWO 16x16 f32 tiles through per-wave LDS scratch (512 floats).
// write: lane holds col=lane&15, rows kb*4+q. read: lane owns (tile=lane>>5,
// row=(lane&31)>>1, 8 cols at cb=(lane&1)*8).
__device__ __forceinline__ void xpose2(float* wscr, const f32x4* acc, int ua, int r, int kb,
                                       int urow, int cb, int usel, float* vals) {
#pragma unroll
  for (int tdx = 0; tdx < 2; ++tdx) {
    f32x4 a = acc[ua + tdx];
    int base = tdx * 256 + kb * 64 + r;
#pragma unroll
    for (int q = 0; q < 4; ++q) wscr[base + q * 16] = a[q];
  }
  asm volatile("s_waitcnt lgkmcnt(0)" ::: "memory");
  __builtin_amdgcn_sched_barrier(0);
  int rb = usel * 256 + urow * 16 + cb;
#pragma unroll
  for (int j = 0; j < 8; ++j) vals[j] = wscr[rb + j];
}

// Block classes: 0 special(0-7,Q), 1 hb(8-103,P), 2 dec1(104-119,P), 3 phix(120-121,P),
//                4 encx/gix(122-185,Q), 5 dec2(186-187,Q), 6 giz(188-251,R), 7 idle
__global__ void __launch_bounds__(512, 2) vrnn_loop(LoopP p) {
  extern __shared__ char lds[];
  const int tid = threadIdx.x, lane = tid & 63, wv = tid >> 6;
  const int r = lane & 15, kb = lane >> 4;
  const int urow = (lane & 31) >> 1, cb = (lane & 1) * 8, usel = lane >> 5;
  const int b = blockIdx.x;
  unsigned bs = 0;

  int cls, uid0 = 0, gizj = 0, wpxb = 0;
  if (b < 8) cls = 0;
  else if (b < 104) { cls = 1; uid0 = 4 * (b - 8); }
  else if (b < 120) { cls = 2; uid0 = 4 * (b - 104); }
  else if (b < 122) { cls = 3; wpxb = b - 120; }
  else if (b < 186) { cls = 4; uid0 = 4 * (b - 122); }
  else if (b < 188) { cls = 5; uid0 = 4 * (b - 186); }
  else if (b < 252) { cls = 6; gizj = b - 188; }
  else cls = 7;

  float* wscr = (float*)(lds + 131072) + wv * 512; // classes 0-5 epilogue scratch

  // ----- one-time LDS weight staging -----
  if (cls == 0) {
    for (int c = tid; c < 8192; c += 512) { // WPZ: 64 units of 2KB (K=64)
      int kg = c & 7, rr = (c >> 3) & 15, u = c >> 7;
      *(float4*)(lds + u * 2048 + (((kg << 4) + rr) << 4)) =
          *(const float4*)(p.WPZ + (size_t)(u * 16 + rr) * 64 + kg * 8);
    }
  } else if (cls == 1) {
    for (int u = 0; u < 4; ++u) stage1024(lds, u * 32768, p.WA + (size_t)(uid0 + u) * 16 * 1024);
  } else if (cls == 2) {
    for (int u = 0; u < 4; ++u) stage1024(lds, u * 32768, p.WDZ + (size_t)(uid0 + u) * 16 * 1024);
  } else if (cls == 3) {
    for (int c = tid; c < 8192; c += 512) { // 32 WPX units of 4KB (K=128)
      int u = c >> 8, kg = c & 15, rr = (c >> 4) & 15;
      *(float4*)(lds + u * 4096 + (((kg << 4) + rr) << 4)) =
          *(const float4*)(p.WPX + (size_t)((wpxb * 32 + u) * 16 + rr) * 128 + kg * 8);
    }
  } else if (cls == 4) {
    for (int u = 0; u < 4; ++u) {
      int uid = uid0 + u;
      const bf16* src = (uid < 64) ? p.WXX + (size_t)uid * 16 * 1024
                                   : p.WIX + (size_t)(uid - 64) * 16 * 1024;
      stage1024(lds, u * 32768, src);
    }
  } else if (cls == 5) {
    for (int u = 0; u < 4; ++u) stage1024(lds, u * 32768, p.WD2 + (size_t)(uid0 + u) * 16 * 1024);
  } else if (cls == 6) {
    for (int g = 0; g < 3; ++g)
      stage1024(lds, g * 32768, p.WIZ + (size_t)(g * 1024 + gizj * 16) * 1024);
  }
  __syncthreads();

  for (int t = 0; t < SEQ; ++t) {
    const int cur = t & 1, oth = cur ^ 1;

    // ================= Phase P =================
    if (cls == 1) { // [prior|ench|gh|dhp] = h @ WA
      const bf16* Arow = p.HB + (size_t)(wv * 16 + r) * HD;
      f32x4 acc[4] = {};
      run_units<4>(Arow, lds, acc, r, kb);
#pragma unroll
      for (int up = 0; up < 4; up += 2) {
        float vals[8];
        xpose2(wscr, acc, up, r, kb, urow, cb, usel, vals);
        int uid = uid0 + up + usel;
        int gm = wv * 16 + urow;
        if (uid < 64) {
          int gn = uid * 16 + cb;
          bf16x8 o;
#pragma unroll
          for (int j = 0; j < 8; ++j) o[j] = (bf16)fmaxf(vals[j] + p.prior_b[gn + j], 0.f);
          cst16(&p.PT[gm * HD + gn], o);
        } else if (uid < 128) {
          int c = (uid - 64) * 16 + cb;
          bf16x8 ex = *(const bf16x8*)(p.ENCX + (size_t)cur * BH + gm * HD + c);
          bf16x8 o;
#pragma unroll
          for (int j = 0; j < 8; ++j) o[j] = (bf16)fmaxf(vals[j] + (float)ex[j], 0.f);
          cst16(&p.ET[gm * HD + c], o);
        } else if (uid < 320) {
          int c = (uid - 128) * 16 + cb;
          f32x4 g0, g1;
#pragma unroll
          for (int j = 0; j < 4; ++j) g0[j] = vals[j] + p.gru_bh[c + j];
#pragma unroll
          for (int j = 0; j < 4; ++j) g1[j] = vals[4 + j] + p.gru_bh[c + 4 + j];
          cst16f(&p.GH[gm * 3072 + c], g0);
          cst16f(&p.GH[gm * 3072 + c + 4], g1);
        } else {
          int c = (uid - 320) * 16 + cb;
          bf16x8 o;
#pragma unroll
          for (int j = 0; j < 8; ++j) o[j] = (bf16)vals[j];
          cst16(&p.DHP[(size_t)cur * BH + gm * HD + c], o);
        }
      }
    } else if (cls == 2 && t > 0) { // dec1_{t-1} = relu(phiz@WDZ + dhp + b)
      const bf16* Arow = p.PHIZ + (size_t)oth * BH + (size_t)(wv * 16 + r) * HD;
      f32x4 acc[4] = {};
      run_units<4>(Arow, lds, acc, r, kb);
#pragma unroll
      for (int up = 0; up < 4; up += 2) {
        float vals[8];
        xpose2(wscr, acc, up, r, kb, urow, cb, usel, vals);
        int c = (uid0 + up + usel) * 16 + cb;
        int gm = wv * 16 + urow;
        bf16x8 dh = *(const bf16x8*)(p.DHP + (size_t)oth * BH + gm * HD + c);
        bf16x8 o;
#pragma unroll
        for (int j = 0; j < 8; ++j)
          o[j] = (bf16)fmaxf(vals[j] + (float)dh[j] + p.dec1_b[c + j], 0.f);
        cst16(&p.DECH[gm * HD + c], o);
      }
    } else if (cls == 3 && t < SEQ - 1) { // phi_x_{t+1}, K=128, 32 units
      bf16x8 af2[4];
      load_af<4>(af2, p.XBF + (size_t)(t + 1) * BATCH * XD, wv * 16 + r, 128, 0, kb);
#pragma unroll 1
      for (int up = 0; up < 32; up += 2) {
        f32x4 acc2[2] = {};
#pragma unroll
        for (int tdx = 0; tdx < 2; ++tdx)
#pragma unroll
          for (int kk = 0; kk < 4; ++kk)
            acc2[tdx] = mfma16(af2[kk],
                               *(const bf16x8*)(lds + (up + tdx) * 4096 +
                                                ((((kk * 4 + kb) << 4) + r) << 4)),
                               acc2[tdx]);
        float vals[8];
        xpose2(wscr, acc2, 0, r, kb, urow, cb, usel, vals);
        int gn = (wpxb * 32 + up + usel) * 16 + cb;
        int gm = wv * 16 + urow;
        bf16x8 o;
#pragma unroll
        for (int j = 0; j < 8; ++j) o[j] = (bf16)fmaxf(vals[j] + p.phx_b[gn + j], 0.f);
        cst16(&p.PHIX[gm * HD + gn], o);
      }
    }
    gbar(p.ARR, p.SUM, ++bs);

    // ================= Phase Q =================
    if (cls == 0) { // meanstd -> z/kld -> phiz
      const int m0 = b * 16;
      const int mat = wv & 3, half = wv >> 2;
      float* sm = (float*)(lds + 131072);
      bf16* zs = (bf16*)(lds + 147456);
      float* red = (float*)(lds + 149760);
      {
        const bf16* Arow = ((mat < 2) ? p.PT : p.ET) + (size_t)(m0 + r) * HD;
        bf16x8 af[32];
#pragma unroll
        for (int kk = 0; kk < 32; ++kk) af[kk] = *(const bf16x8*)(Arow + kk * 32 + kb * 8);
        const float* bw = mat == 0 ? p.pm_b : mat == 1 ? p.ps_b : mat == 2 ? p.em_b : p.es_b;
#pragma unroll 1
        for (int nt = 0; nt < 2; ++nt) {
          int colb = half * 32 + nt * 16;
          f32x4 acc = {};
#pragma unroll
          for (int kk = 0; kk < 32; ++kk)
            acc = mfma16(af[kk],
                         *(const bf16x8*)(p.WB + (size_t)(mat * 64 + colb + r) * 1024 +
                                          kk * 32 + kb * 8),
                         acc);
#pragma unroll
          for (int qq = 0; qq < 4; ++qq)
            sm[mat * 1024 + (kb * 4 + qq) * 64 + colb + r] = acc[qq] + bw[colb + r];
        }
      }
      __syncthreads();
      float kacc = 0.f;
      for (int e = tid; e < 1024; e += 512) {
        int row = e >> 6, col = e & 63;
        float pm = sm[row * 64 + col], ps = sm[1024 + row * 64 + col];
        float em = sm[2048 + row * 64 + col], es = sm[3072 + row * 64 + col];
        float ev = p.eps[((size_t)t * BATCH + m0 + row) * ZD + col];
        zs[row * 72 + col] = (bf16)(em + ev * __expf(0.5f * es));
        float dm = em - pm;
        kacc += 1.f + es - dm * dm - __expf(es - ps);
      }
#pragma unroll
      for (int off = 32; off; off >>= 1) kacc += __shfl_down(kacc, off, 64);
      if (lane == 0) red[wv] = kacc;
      __syncthreads(); // sm dead from here: reuse as wscr
      if (tid == 0) {
        float ss = 0.f;
        for (int i = 0; i < 8; ++i) ss += red[i];
        p.KLD[t * 8 + b] = ss;
      }
      bf16x8 afz[2];
      afz[0] = *(const bf16x8*)(zs + r * 72 + kb * 8);
      afz[1] = *(const bf16x8*)(zs + r * 72 + 32 + kb * 8);
#pragma unroll 1
      for (int jp = 0; jp < 8; jp += 2) {
        f32x4 acc2[2] = {};
#pragma unroll
        for (int tdx = 0; tdx < 2; ++tdx) {
          int u = wv * 8 + jp + tdx;
#pragma unroll
          for (int kk = 0; kk < 2; ++kk)
            acc2[tdx] = mfma16(afz[kk],
                               *(const bf16x8*)(lds + u * 2048 +
                                                ((((kk * 4 + kb) << 4) + r) << 4)),
                               acc2[tdx]);
        }
        float vals[8];
        xpose2(wscr, acc2, 0, r, kb, urow, cb, usel, vals);
        int gn = (wv * 8 + jp + usel) * 16 + cb;
        int gm = m0 + urow;
        bf16x8 o;
#pragma unroll
        for (int j = 0; j < 8; ++j) o[j] = (bf16)fmaxf(vals[j] + p.pz_b[gn + j], 0.f);
        cst16(&p.PHIZ[(size_t)cur * BH + gm * HD + gn], o);
      }
    } else if (cls == 4 && t < SEQ - 1) { // [encx|gix]_{t+1} = phix @ [WXX|WIX]
      const bf16* Arow = p.PHIX + (size_t)(wv * 16 + r) * HD;
      f32x4 acc[4] = {};
      run_units<4>(Arow, lds, acc, r, kb);
#pragma unroll
      for (int up = 0; up < 4; up += 2) {
        float vals[8];
        xpose2(wscr, acc, up, r, kb, urow, cb, usel, vals);
        int uid = uid0 + up + usel;
        int gm = wv * 16 + urow;
        if (uid < 64) {
          int c = uid * 16 + cb;
          bf16x8 o;
#pragma unroll
          for (int j = 0; j < 8; ++j) o[j] = (bf16)(vals[j] + p.enc_b[c + j]);
          cst16(&p.ENCX[(size_t)oth * BH + gm * HD + c], o);
        } else {
          int c = (uid - 64) * 16 + cb;
          f32x4 g0, g1;
#pragma unroll
          for (int j = 0; j < 4; ++j) g0[j] = vals[j] + p.gru_bi[c + j];
#pragma unroll
          for (int j = 0; j < 4; ++j) g1[j] = vals[4 + j] + p.gru_bi[c + 4 + j];
          cst16f(&p.GIX[(size_t)oth * B3 + gm * 3072 + c], g0);
          cst16f(&p.GIX[(size_t)oth * B3 + gm * 3072 + c + 4], g1);
        }
      }
    } else if (cls == 5 && t > 0) { // dec2_{t-1} + recon + sigmoid
      const bf16* Arow = p.DECH + (size_t)(wv * 16 + r) * HD;
      f32x4 acc[4] = {};
      run_units<4>(Arow, lds, acc, r, kb);
      float racc = 0.f;
#pragma unroll
      for (int up = 0; up < 4; up += 2) {
        float vals[8];
        xpose2(wscr, acc, up, r, kb, urow, cb, usel, vals);
        int c = (uid0 + up + usel) * 16 + cb;
        int gm = wv * 16 + urow;
        size_t oi = ((size_t)(t - 1) * BATCH + gm) * XD + c;
#pragma unroll
        for (int j = 0; j < 8; ++j) {
          float l = vals[j] + p.dec2_b[c + j];
          p.out[2 + oi + j] = sigmoidf_(l);
          float spp = fmaxf(l, 0.f) + log1pf(__expf(-fabsf(l)));
          racc += spp - p.x[oi + j] * l;
        }
      }
#pragma unroll
      for (int off = 32; off; off >>= 1) racc += __shfl_down(racc, off, 64);
      if (lane == 0) p.RPART[(t - 1) * 64 + uid0 * 2 + wv] = racc;
    }
    gbar(p.ARR, p.SUM, ++bs);

    // ================= Phase R: fused giz + GRU =================
    if (cls == 6) {
      float* scR = (float*)(lds + 98304); // [2 khalf][4 mtg][3 g][16][16] f32
      const int khalf = wv >> 2, mtg = wv & 3;
#pragma unroll 1
      for (int pass = 0; pass < 2; ++pass) {
        int mt = mtg + 4 * pass;
        const bf16* Arow = p.PHIZ + (size_t)cur * BH + (size_t)(mt * 16 + r) * HD;
        bf16x8 af[16];
#pragma unroll
        for (int kk = 0; kk < 16; ++kk)
          af[kk] = *(const bf16x8*)(Arow + khalf * 512 + kk * 32 + kb * 8);
        f32x4 a3[3] = {};
#pragma unroll
        for (int kk = 0; kk < 16; ++kk) {
          bf16x8 a = af[kk];
#pragma unroll
          for (int g = 0; g < 3; ++g)
            a3[g] = mfma16(a,
                           *(const bf16x8*)(lds + g * 32768 +
                                            (((((khalf * 16 + kk) * 4 + kb) << 4) + r) << 4)),
                           a3[g]);
        }
#pragma unroll
        for (int g = 0; g < 3; ++g)
#pragma unroll
          for (int q = 0; q < 4; ++q)
            scR[khalf * 3072 + mtg * 768 + g * 256 + (kb * 4 + q) * 16 + r] = a3[g][q];
        __syncthreads();
        if (tid < 128) {
          int mtg2 = tid >> 5, row = (tid & 31) >> 1, cb2 = (tid & 1) * 8;
          int gm = (mtg2 + 4 * pass) * 16 + row;
          int c = gizj * 16 + cb2;
          int base = mtg2 * 768 + row * 16 + cb2;
          float iv[3][8], hv[3][8];
#pragma unroll
          for (int g = 0; g < 3; ++g) {
            f32x4 i0 = *(const f32x4*)(p.GIX + (size_t)cur * B3 + gm * 3072 + g * 1024 + c);
            f32x4 i1 = *(const f32x4*)(p.GIX + (size_t)cur * B3 + gm * 3072 + g * 1024 + c + 4);
            f32x4 h0 = *(const f32x4*)(p.GH + gm * 3072 + g * 1024 + c);
            f32x4 h1 = *(const f32x4*)(p.GH + gm * 3072 + g * 1024 + c + 4);
#pragma unroll
            for (int j = 0; j < 8; ++j) {
              float part = scR[base + g * 256 + j] + scR[3072 + base + g * 256 + j];
              iv[g][j] = part + ((j < 4) ? i0[j] : i1[j - 4]);
              hv[g][j] = (j < 4) ? h0[j] : h1[j - 4];
            }
          }
          f32x4 hc0 = *(const f32x4*)(p.H + gm * HD + c);
          f32x4 hc1 = *(const f32x4*)(p.H + gm * HD + c + 4);
          f32x4 hn0, hn1;
          bf16x8 o;
#pragma unroll
          for (int j = 0; j < 8; ++j) {
            float rr2 = sigmoidf_(iv[0][j] + hv[0][j]);
            float zg = sigmoidf_(iv[1][j] + hv[1][j]);
            float nn = tanhf(iv[2][j] + rr2 * hv[2][j]);
            float hvv = (j < 4) ? hc0[j] : hc1[j - 4];
            float hnew = (1.f - zg) * nn + zg * hvv;
            if (j < 4) hn0[j] = hnew; else hn1[j - 4] = hnew;
            o[j] = (bf16)hnew;
          }
          *(f32x4*)(p.H + gm * HD + c) = hn0;
          *(f32x4*)(p.H + gm * HD + c + 4) = hn1;
          cst16(&p.HB[gm * HD + c], o);
        }
        __syncthreads();
      }
    }
    gbar(p.ARR, p.SUM, ++bs);
  }
}

// ---------------- epilogue dec2 for t=255 -------------------------------------------
__global__ void dec2_last(const bf16* __restrict__ A, const bf16* __restrict__ W,
                          const float* __restrict__ x, const float* __restrict__ b2,
                          float* __restrict__ out, float* __restrict__ rpart) {
  const int lane = threadIdx.x & 63;
  const int r = lane & 15, kb = lane >> 4;
  const int w = blockIdx.x * 4 + (threadIdx.x >> 6); // 0..63
  const int m0 = (w & 7) * 16, n0 = (w >> 3) * 16;
  f32x4 acc[1][1] = {};
  const bf16* a0 = A + (size_t)(m0 + r) * HD + kb * 8;
  const bf16* b0 = W + (size_t)(n0 + r) * HD + kb * 8;
  mma_block<1, 1>(a0, 0, b0, (size_t)16 * HD, HD, acc);
  float racc = 0.f;
#pragma unroll
  for (int q = 0; q < 4; ++q) {
    int gm = m0 + kb * 4 + q, gn = n0 + r;
    float l = acc[0][0][q] + b2[gn];
    size_t oi = ((size_t)255 * BATCH + gm) * XD + gn;
    out[2 + oi] = sigmoidf_(l);
    float spp = fmaxf(l, 0.f) + log1pf(__expf(-fabsf(l)));
    racc += spp - x[oi] * l;
  }
#pragma unroll
  for (int off = 32; off; off >>= 1) racc += __shfl_down(racc, off, 64);
  if (lane == 0) rpart[255 * 64 + w] = racc;
}

__global__ void finalize_k(const float* __restrict__ rp, const float* __restrict__ kp,
                           float* __restrict__ out) {
  __shared__ float s[256];
  int tid = threadIdx.x;
  float a = 0.f;
  for (int i = tid; i < 256 * 64; i += 256) a += rp[i];
  s[tid] = a;
  __syncthreads();
  for (int off = 128; off > 0; off >>= 1) {
    if (tid < off) s[tid] += s[tid + off];
    __syncthreads();
  }
  if (tid == 0) out[0] = s[0] / (float)BATCH;
  __syncthreads();
  float bb = 0.f;
  for (int i = tid; i < 2048; i += 256) bb += kp[i];
  s[tid] = bb;
  __syncthreads();
  for (int off = 128; off > 0; off >>= 1) {
    if (tid < off) s[tid] += s[tid + off];
    __syncthreads();
  }
  if (tid == 0) out[1] = -0.5f * s[0] / (float)BATCH;
}

__global__ void sentinel_k(float* out) {
  if (threadIdx.x == 0) { out[0] = 1e9f; out[1] = 1e9f; }
}

// =====================================================================================
extern "C" void kernel_launch(void* const* d_in, const int* in_sizes, int n_in, void* d_out,
                              int out_size, void* d_ws, size_t ws_size, hipStream_t stream) {
  const float* x = (const float*)d_in[0];
  const float* eps = (const float*)d_in[1];
  const float* phi_x_W = (const float*)d_in[2];
  const float* phi_x_b = (const float*)d_in[3];
  const float* enc_W = (const float*)d_in[4];
  const float* enc_b = (const float*)d_in[5];
  const float* enc_mean_W = (const float*)d_in[6];
  const float* enc_mean_b = (const float*)d_in[7];
  const float* enc_std_W = (const float*)d_in[8];
  const float* enc_std_b = (const float*)d_in[9];
  const float* prior_W = (const float*)d_in[10];
  const float* prior_b = (const float*)d_in[11];
  const float* prior_mean_W = (const float*)d_in[12];
  const float* prior_mean_b = (const float*)d_in[13];
  const float* prior_std_W = (const float*)d_in[14];
  const float* prior_std_b = (const float*)d_in[15];
  const float* phi_z_W = (const float*)d_in[16];
  const float* phi_z_b = (const float*)d_in[17];
  const float* dec1_W = (const float*)d_in[18];
  const float* dec1_b = (const float*)d_in[19];
  const float* dec2_W = (const float*)d_in[20];
  const float* dec2_b = (const float*)d_in[21];
  const float* gru_Wi = (const float*)d_in[22];
  const float* gru_Wh = (const float*)d_in[23];
  const float* gru_bi = (const float*)d_in[24];
  const float* gru_bh = (const float*)d_in[25];
  float* out = (float*)d_out;

  char* w = (char*)d_ws;
  auto carve = [&](size_t bytes) {
    char* pp = w;
    w += (bytes + 255) & ~(size_t)255;
    return pp;
  };
  bf16* WA = (bf16*)carve((size_t)6144 * HD * 2);  // [prior;ench;gh;dhp]
  bf16* WB = (bf16*)carve((size_t)256 * HD * 2);   // [pm;ps;em;es]
  bf16* WPZ = (bf16*)carve((size_t)HD * ZD * 2);
  bf16* WIZ = (bf16*)carve((size_t)3072 * HD * 2); // gru_Wi[:,1024:]
  bf16* WIX = (bf16*)carve((size_t)3072 * HD * 2); // gru_Wi[:,:1024]
  bf16* WXX = (bf16*)carve((size_t)HD * HD * 2);   // enc_W[:,:1024]
  bf16* WPX = (bf16*)carve((size_t)HD * XD * 2);
  bf16* WDZ = (bf16*)carve((size_t)HD * HD * 2);   // dec1_W[:,:1024]
  bf16* WD2 = (bf16*)carve((size_t)XD * HD * 2);
  bf16* XBF = (bf16*)carve((size_t)MROWS * XD * 2);
  float* H = (float*)carve((size_t)BH * 4);
  bf16* HB = (bf16*)carve((size_t)BH * 2);
  bf16* PT = (bf16*)carve((size_t)BH * 2);
  bf16* ET = (bf16*)carve((size_t)BH * 2);
  float* GH = (float*)carve((size_t)B3 * 4);
  bf16* PHIX = (bf16*)carve((size_t)BH * 2);
  bf16* ENCX = (bf16*)carve((size_t)2 * BH * 2);
  bf16* PHIZ = (bf16*)carve((size_t)2 * BH * 2);
  bf16* DHP = (bf16*)carve((size_t)2 * BH * 2);
  bf16* DECH = (bf16*)carve((size_t)BH * 2);
  float* GIX = (float*)carve((size_t)2 * B3 * 4);
  float* KLD = (float*)carve((size_t)SEQ * 8 * 4);
  float* RPART = (float*)carve((size_t)SEQ * 64 * 4);
  unsigned* ARR = (unsigned*)carve((size_t)NBLK * 32 * 4);
  unsigned* SUM = (unsigned*)carve((size_t)16 * 32 * 4);
  if ((size_t)(w - (char*)d_ws) > ws_size) {
    sentinel_k<<<1, 64, 0, stream>>>(out);
    return;
  }

  auto cvt = [&](bf16* dst, const float* src, long n, int cols, int ld, int off) {
    int grid = (int)std::min((n + 255) / 256, (long)2048);
    cvt_k<<<grid, 256, 0, stream>>>(dst, src, n, cols, ld, off);
  };
  cvt(WA, prior_W, (long)HD * HD, HD, HD, 0);
  cvt(WA + (size_t)HD * HD, enc_W, (long)HD * HD, HD, 2 * HD, HD);
  cvt(WA + (size_t)2048 * HD, gru_Wh, (long)3072 * HD, HD, HD, 0);
  cvt(WA + (size_t)5120 * HD, dec1_W, (long)HD * HD, HD, 2 * HD, HD);
  cvt(WB, prior_mean_W, (long)ZD * HD, HD, HD, 0);
  cvt(WB + (size_t)64 * HD, prior_std_W, (long)ZD * HD, HD, HD, 0);
  cvt(WB + (size_t)128 * HD, enc_mean_W, (long)ZD * HD, HD, HD, 0);
  cvt(WB + (size_t)192 * HD, enc_std_W, (long)ZD * HD, HD, HD, 0);
  cvt(WPZ, phi_z_W, (long)HD * ZD, ZD, ZD, 0);
  cvt(WIZ, gru_Wi, (long)3072 * HD, HD, 2 * HD, HD);
  cvt(WIX, gru_Wi, (long)3072 * HD, HD, 2 * HD, 0);
  cvt(WXX, enc_W, (long)HD * HD, HD, 2 * HD, 0);
  cvt(WPX, phi_x_W, (long)HD * XD, XD, XD, 0);
  cvt(WDZ, dec1_W, (long)HD * HD, HD, 2 * HD, 0);
  cvt(WD2, dec2_W, (long)XD * HD, HD, HD, 0);
  cvt(XBF, x, (long)MROWS * XD, XD, XD, 0);

  hipMemsetAsync(H, 0, (size_t)BH * 4, stream);
  hipMemsetAsync(HB, 0, (size_t)BH * 2, stream);
  hipMemsetAsync(RPART, 0, (size_t)SEQ * 64 * 4, stream);
  hipMemsetAsync(ARR, 0, (size_t)NBLK * 32 * 4, stream);
  hipMemsetAsync(SUM, 0, (size_t)16 * 32 * 4, stream);

  // prologue: phi_x_0 -> encx_0, gix_0 (slot 0)
  Epi e1{PHIX, nullptr, phi_x_b, nullptr, 1, HD};
  gemm_bt<2, 2><<<32, 256, 0, stream>>>(XBF, XD, WPX, XD, BATCH, HD, XD, e1);
  Epi e2{ENCX, nullptr, enc_b, nullptr, 0, HD};
  gemm_bt<2, 2><<<32, 256, 0, stream>>>(PHIX, HD, WXX, HD, BATCH, HD, HD, e2);
  Epi e3{nullptr, GIX, gru_bi, nullptr, 0, 3072};
  gemm_bt<2, 2><<<96, 256, 0, stream>>>(PHIX, HD, WIX, HD, BATCH, 3072, HD, e3);

  LoopP lp;
  lp.WA = WA; lp.WB = WB; lp.WPZ = WPZ; lp.WIZ = WIZ; lp.WIX = WIX; lp.WXX = WXX;
  lp.WPX = WPX; lp.WDZ = WDZ; lp.WD2 = WD2; lp.XBF = XBF;
  lp.HB = HB; lp.PT = PT; lp.ET = ET; lp.PHIX = PHIX; lp.ENCX = ENCX; lp.PHIZ = PHIZ;
  lp.DHP = DHP; lp.DECH = DECH;
  lp.H = H; lp.GH = GH; lp.GIX = GIX; lp.KLD = KLD; lp.RPART = RPART; lp.out = out;
  lp.ARR = ARR; lp.SUM = SUM;
  lp.eps = eps; lp.x = x;
  lp.prior_b = prior_b; lp.gru_bh = gru_bh; lp.gru_bi = gru_bi;
  lp.pm_b = prior_mean_b; lp.ps_b = prior_std_b; lp.em_b = enc_mean_b; lp.es_b = enc_std_b;
  lp.pz_b = phi_z_b; lp.phx_b = phi_x_b; lp.enc_b = enc_b; lp.dec1_b = dec1_b;
  lp.dec2_b = dec2_b;

  hipFuncSetAttribute(reinterpret_cast<const void*>(vrnn_loop),
                      hipFuncAttributeMaxDynamicSharedMemorySize, DYN_LDS);
  void* args[] = {&lp};
  hipLaunchCooperativeKernel(reinterpret_cast<const void*>(vrnn_loop), dim3(NBLK), dim3(512),
                             args, DYN_LDS, stream);

  // epilogue: dec1_255 (slot 1), dec2_255, losses
  Epi e4{DECH, nullptr, dec1_b, DHP + (size_t)1 * BH, 1, HD};
  gemm_bt<2, 2><<<32, 256, 0, stream>>>(PHIZ + (size_t)1 * BH, HD, WDZ, HD, BATCH, HD, HD, e4);
  dec2_last<<<16, 256, 0, stream>>>(DECH, WD2, x, dec2_b, out, RPART);
  finalize_k<<<1, 256, 0, stream>>>(RPART, KLD, out);
}

// Round 13
// 20991.049 us; speedup vs baseline: 1.5527x; 1.1428x over previous
//
#include <hip/hip_runtime.h>
#include <algorithm>

typedef __bf16 bf16;
typedef __bf16 bf16x8 __attribute__((ext_vector_type(8)));
typedef float f32x4 __attribute__((ext_vector_type(4)));
typedef unsigned long long u64;

// SEQ=256, B=128, XD=128, HD=1024, ZD=64
#define SEQ 256
#define BATCH 128
#define XD 128
#define HD 1024
#define ZD 64
#define MROWS (SEQ * BATCH)
#define BH (BATCH * HD)   // 131072
#define B3 (BATCH * 3072) // 393216
#define DYN_LDS 154432
#define NBLK 256

__device__ __forceinline__ f32x4 mfma16(bf16x8 a, bf16x8 b, f32x4 c) {
  return __builtin_amdgcn_mfma_f32_16x16x32_bf16(a, b, c, 0, 0, 0);
}
__device__ __forceinline__ float sigmoidf_(float x) { return 1.f / (1.f + __expf(-x)); }

// ---- 16B write-through stores (cross-block visible; proven semantics) --------------
__device__ __forceinline__ void cst16(bf16* p, bf16x8 v) {
  asm volatile("global_store_dwordx4 %0, %1, off sc0 sc1" ::"v"(p), "v"(v) : "memory");
}
__device__ __forceinline__ void cst16f(float* p, f32x4 v) {
  asm volatile("global_store_dwordx4 %0, %1, off sc0 sc1" ::"v"(p), "v"(v) : "memory");
}

// ---- two-level tree grid barrier; agent-scope acquire fence (invalidate caches) ----
__device__ __forceinline__ void gbar(unsigned* arr, unsigned* sum, unsigned serial) {
  asm volatile("s_waitcnt vmcnt(0) lgkmcnt(0)" ::: "memory");
  __syncthreads();
  const int tid = threadIdx.x;
  const int bid = blockIdx.x;
  if (tid == 0)
    __hip_atomic_store(arr + (size_t)bid * 32, serial, __ATOMIC_RELAXED,
                       __HIP_MEMORY_SCOPE_AGENT);
  if ((bid & 15) == 0 && tid < 16) {
    const unsigned* f = arr + (size_t)((bid & ~15) + tid) * 32;
    while (__hip_atomic_load(f, __ATOMIC_RELAXED, __HIP_MEMORY_SCOPE_AGENT) < serial)
      __builtin_amdgcn_s_sleep(2);
  }
  __syncthreads();
  if ((bid & 15) == 0 && tid == 0)
    __hip_atomic_store(sum + (size_t)(bid >> 4) * 32, serial, __ATOMIC_RELAXED,
                       __HIP_MEMORY_SCOPE_AGENT);
  if (tid < 16) {
    const unsigned* f = sum + (size_t)tid * 32;
    while (__hip_atomic_load(f, __ATOMIC_RELAXED, __HIP_MEMORY_SCOPE_AGENT) < serial)
      __builtin_amdgcn_s_sleep(2);
  }
  __builtin_amdgcn_fence(__ATOMIC_ACQUIRE, "agent"); // invalidate L1/L2: plain loads OK
  __syncthreads();
}

// ---------- generic mma (global A, global B) for prologue/tail kernels --------------
template <int MT, int NT>
__device__ __forceinline__ void mma_block(const bf16* __restrict__ a0, size_t aStride,
                                          const bf16* __restrict__ b0, size_t bStride,
                                          int K, f32x4 acc[MT][NT]) {
#pragma unroll 2
  for (int k = 0; k < K; k += 32) {
    bf16x8 af[MT], bfr[NT];
#pragma unroll
    for (int i = 0; i < MT; ++i) af[i] = *(const bf16x8*)(a0 + (size_t)i * aStride + k);
#pragma unroll
    for (int j = 0; j < NT; ++j) bfr[j] = *(const bf16x8*)(b0 + (size_t)j * bStride + k);
#pragma unroll
    for (int i = 0; i < MT; ++i)
#pragma unroll
      for (int j = 0; j < NT; ++j) acc[i][j] = mfma16(af[i], bfr[j], acc[i][j]);
  }
}

// ---------------- fp32 -> bf16 conversion (column slicing for concat splits) --------
__global__ void cvt_k(bf16* __restrict__ dst, const float* __restrict__ src, long n,
                      int cols, int src_ld, int col_off) {
  long i = (long)blockIdx.x * blockDim.x + threadIdx.x;
  long stride = (long)gridDim.x * blockDim.x;
  for (; i < n; i += stride) {
    long row = i / cols;
    int c = (int)(i - row * cols);
    dst[i] = (bf16)src[row * (long)src_ld + col_off + c];
  }
}

// ---------------- generic GEMM (B^T) for prologue ----------------------------------
struct Epi {
  bf16* C;
  float* Cf;
  const float* bias;
  const bf16* add;
  int relu;
  int ldc;
};

template <int MT, int NT>
__global__ void gemm_bt(const bf16* __restrict__ A, int lda, const bf16* __restrict__ B,
                        int ldb, int M, int N, int K, Epi e) {
  const int lane = threadIdx.x & 63;
  const int r = lane & 15, kb = lane >> 4;
  const int gw = blockIdx.x * (blockDim.x >> 6) + (threadIdx.x >> 6);
  const int nw = gridDim.x * (blockDim.x >> 6);
  const int ntm = M / (16 * MT), ntn = N / (16 * NT);
  for (int task = gw; task < ntm * ntn; task += nw) {
    int mt = task % ntm, nt = task / ntm;
    int m0 = mt * 16 * MT, n0 = nt * 16 * NT;
    f32x4 acc[MT][NT] = {};
    const bf16* a0 = A + (size_t)(m0 + r) * lda + kb * 8;
    const bf16* b0 = B + (size_t)(n0 + r) * ldb + kb * 8;
    mma_block<MT, NT>(a0, (size_t)16 * lda, b0, (size_t)16 * ldb, K, acc);
#pragma unroll
    for (int i = 0; i < MT; ++i)
#pragma unroll
      for (int j = 0; j < NT; ++j)
#pragma unroll
        for (int q = 0; q < 4; ++q) {
          size_t gm = (size_t)m0 + i * 16 + kb * 4 + q;
          int gn = n0 + j * 16 + r;
          float v = acc[i][j][q] + e.bias[gn];
          if (e.add) v += (float)e.add[gm * e.ldc + gn];
          if (e.relu) v = fmaxf(v, 0.f);
          if (e.Cf) e.Cf[gm * e.ldc + gn] = v;
          else e.C[gm * e.ldc + gn] = (bf16)v;
        }
  }
}

// ===================== the LDS-weight-pinned recurrence ==============================
struct LoopP {
  const bf16 *WA, *WB, *WPZ, *WIZ, *WIX, *WXX, *WPX, *WDZ, *WD2, *XBF;
  bf16 *HB, *PT, *ET, *PHIX, *ENCX, *PHIZ, *DHP, *DECH;
  float *H, *GH, *GIX, *KLD, *RPART, *out;
  unsigned *ARR, *SUM, *PFLAG;
  const float *eps, *x;
  const float *prior_b, *gru_bh, *gru_bi, *pm_b, *ps_b, *em_b, *es_b, *pz_b, *phx_b,
      *enc_b, *dec1_b, *dec2_b;
};

// stage 16 rows x K=1024 into k-major LDS unit: [128 kg][16 row][16B]
__device__ __forceinline__ void stage1024(char* lds, int off, const bf16* src) {
  for (int c = threadIdx.x; c < 2048; c += 512) {
    int kg = c & 127, rr = c >> 7;
    *(float4*)(lds + off + (((kg << 4) + rr) << 4)) =
        *(const float4*)(src + (size_t)rr * 1024 + kg * 8);
  }
}

template <int KK>
__device__ __forceinline__ void load_af(bf16x8* af, const bf16* A, int row, int lda, int k0,
                                        int kb) {
#pragma unroll
  for (int kk = 0; kk < KK; ++kk)
    af[kk] = *(const bf16x8*)(A + (size_t)row * lda + k0 + kk * 32 + kb * 8);
}

// NU weight units (32KB slabs); A-row via plain cached 16B loads (L1-coalesced)
template <int NU>
__device__ __forceinline__ void run_units(const bf16* Arow, const char* slab0, f32x4* acc,
                                          int r, int kb) {
  bf16x8 af[32];
#pragma unroll
  for (int kk = 0; kk < 32; ++kk) af[kk] = *(const bf16x8*)(Arow + kk * 32 + kb * 8);
#pragma unroll
  for (int u = 0; u < NU; ++u)
#pragma unroll
    for (int kk = 0; kk < 32; ++kk)
      acc[u] = mfma16(af[kk],
                      *(const bf16x8*)(slab0 + u * 32768 + ((((kk * 4 + kb) << 4) + r) << 4)),
                      acc[u]);
}

// transpose TWO 16x16 f32 tiles through per-wave padded LDS scratch.
// layout: tile stride 328 floats, row stride 20 (pad -> conflict-free-ish, 16B aligned).
__device__ __forceinline__ void xpose2(float* wscr, const f32x4* acc, int ua, int r, int kb,
                                       int urow, int cb, int usel, float* vals) {
#pragma unroll
  for (int tdx = 0; tdx < 2; ++tdx) {
    f32x4 a = acc[ua + tdx];
    int base = tdx * 328 + (kb * 4) * 20 + r;
#pragma unroll
    for (int q = 0; q < 4; ++q) wscr[base + q * 20] = a[q];
  }
  asm volatile("s_waitcnt lgkmcnt(0)" ::: "memory");
  __builtin_amdgcn_sched_barrier(0);
  int rb = usel * 328 + urow * 20 + cb;
#pragma unroll
  for (int j = 0; j < 8; ++j) vals[j] = wscr[rb + j];
}

// Block classes: 0 special(0-7,Q), 1 hb(8-103,P), 2 dec1(104-119,P), 3 phix(120-121,P),
//                4 encx/gix(122-185,Q), 5 dec2(186-187,Q), 6 giz(188-251,Q via PFLAG)
__global__ void __launch_bounds__(512, 1) vrnn_loop(LoopP p) {
  extern __shared__ char lds[];
  const int tid = threadIdx.x, lane = tid & 63, wv = tid >> 6;
  const int r = lane & 15, kb = lane >> 4;
  const int urow = (lane & 31) >> 1, cb = (lane & 1) * 8, usel = lane >> 5;
  const int b = blockIdx.x;
  unsigned bs = 0;

  int cls, uid0 = 0, gizj = 0, wpxb = 0;
  if (b < 8) cls = 0;
  else if (b < 104) { cls = 1; uid0 = 4 * (b - 8); }
  else if (b < 120) { cls = 2; uid0 = 4 * (b - 104); }
  else if (b < 122) { cls = 3; wpxb = b - 120; }
  else if (b < 186) { cls = 4; uid0 = 4 * (b - 122); }
  else if (b < 188) { cls = 5; uid0 = 4 * (b - 186); }
  else if (b < 252) { cls = 6; gizj = b - 188; }
  else cls = 7;

  float* wscr = (float*)(lds + 131072) + wv * 656; // classes 0-5 epilogue scratch

  // ----- one-time LDS weight staging -----
  if (cls == 0) {
    for (int c = tid; c < 8192; c += 512) { // WPZ: 64 units of 2KB (K=64)
      int kg = c & 7, rr = (c >> 3) & 15, u = c >> 7;
      *(float4*)(lds + u * 2048 + (((kg << 4) + rr) << 4)) =
          *(const float4*)(p.WPZ + (size_t)(u * 16 + rr) * 64 + kg * 8);
    }
  } else if (cls == 1) {
    for (int u = 0; u < 4; ++u) stage1024(lds, u * 32768, p.WA + (size_t)(uid0 + u) * 16 * 1024);
  } else if (cls == 2) {
    for (int u = 0; u < 4; ++u) stage1024(lds, u * 32768, p.WDZ + (size_t)(uid0 + u) * 16 * 1024);
  } else if (cls == 3) {
    for (int c = tid; c < 8192; c += 512) { // 32 WPX units of 4KB (K=128)
      int u = c >> 8, kg = c & 15, rr = (c >> 4) & 15;
      *(float4*)(lds + u * 4096 + (((kg << 4) + rr) << 4)) =
          *(const float4*)(p.WPX + (size_t)((wpxb * 32 + u) * 16 + rr) * 128 + kg * 8);
    }
  } else if (cls == 4) {
    for (int u = 0; u < 4; ++u) {
      int uid = uid0 + u;
      const bf16* src = (uid < 64) ? p.WXX + (size_t)uid * 16 * 1024
                                   : p.WIX + (size_t)(uid - 64) * 16 * 1024;
      stage1024(lds, u * 32768, src);
    }
  } else if (cls == 5) {
    for (int u = 0; u < 4; ++u) stage1024(lds, u * 32768, p.WD2 + (size_t)(uid0 + u) * 16 * 1024);
  } else if (cls == 6) {
    for (int g = 0; g < 3; ++g)
      stage1024(lds, g * 32768, p.WIZ + (size_t)(g * 1024 + gizj * 16) * 1024);
  }
  __syncthreads();

  for (int t = 0; t < SEQ; ++t) {
    const int cur = t & 1, oth = cur ^ 1;

    // ================= Phase P =================
    if (cls == 1) { // [prior|ench|gh|dhp] = h @ WA
      const bf16* Arow = p.HB + (size_t)(wv * 16 + r) * HD;
      f32x4 acc[4] = {};
      run_units<4>(Arow, lds, acc, r, kb);
#pragma unroll
      for (int up = 0; up < 4; up += 2) {
        float vals[8];
        xpose2(wscr, acc, up, r, kb, urow, cb, usel, vals);
        int uid = uid0 + up + usel;
        int gm = wv * 16 + urow;
        if (uid < 64) {
          int gn = uid * 16 + cb;
          bf16x8 o;
#pragma unroll
          for (int j = 0; j < 8; ++j) o[j] = (bf16)fmaxf(vals[j] + p.prior_b[gn + j], 0.f);
          cst16(&p.PT[gm * HD + gn], o);
        } else if (uid < 128) {
          int c = (uid - 64) * 16 + cb;
          bf16x8 ex = *(const bf16x8*)(p.ENCX + (size_t)cur * BH + gm * HD + c);
          bf16x8 o;
#pragma unroll
          for (int j = 0; j < 8; ++j) o[j] = (bf16)fmaxf(vals[j] + (float)ex[j], 0.f);
          cst16(&p.ET[gm * HD + c], o);
        } else if (uid < 320) {
          int c = (uid - 128) * 16 + cb;
          f32x4 g0, g1;
#pragma unroll
          for (int j = 0; j < 4; ++j) g0[j] = vals[j] + p.gru_bh[c + j];
#pragma unroll
          for (int j = 0; j < 4; ++j) g1[j] = vals[4 + j] + p.gru_bh[c + 4 + j];
          cst16f(&p.GH[gm * 3072 + c], g0);
          cst16f(&p.GH[gm * 3072 + c + 4], g1);
        } else {
          int c = (uid - 320) * 16 + cb;
          bf16x8 o;
#pragma unroll
          for (int j = 0; j < 8; ++j) o[j] = (bf16)vals[j];
          cst16(&p.DHP[(size_t)cur * BH + gm * HD + c], o);
        }
      }
    } else if (cls == 2 && t > 0) { // dec1_{t-1} = relu(phiz@WDZ + dhp + b)
      const bf16* Arow = p.PHIZ + (size_t)oth * BH + (size_t)(wv * 16 + r) * HD;
      f32x4 acc[4] = {};
      run_units<4>(Arow, lds, acc, r, kb);
#pragma unroll
      for (int up = 0; up < 4; up += 2) {
        float vals[8];
        xpose2(wscr, acc, up, r, kb, urow, cb, usel, vals);
        int c = (uid0 + up + usel) * 16 + cb;
        int gm = wv * 16 + urow;
        bf16x8 dh = *(const bf16x8*)(p.DHP + (size_t)oth * BH + gm * HD + c);
        bf16x8 o;
#pragma unroll
        for (int j = 0; j < 8; ++j)
          o[j] = (bf16)fmaxf(vals[j] + (float)dh[j] + p.dec1_b[c + j], 0.f);
        cst16(&p.DECH[gm * HD + c], o);
      }
    } else if (cls == 3 && t < SEQ - 1) { // phi_x_{t+1}, K=128, 32 units
      bf16x8 af2[4];
      load_af<4>(af2, p.XBF + (size_t)(t + 1) * BATCH * XD, wv * 16 + r, 128, 0, kb);
#pragma unroll 1
      for (int up = 0; up < 32; up += 2) {
        f32x4 acc2[2] = {};
#pragma unroll
        for (int tdx = 0; tdx < 2; ++tdx)
#pragma unroll
          for (int kk = 0; kk < 4; ++kk)
            acc2[tdx] = mfma16(af2[kk],
                               *(const bf16x8*)(lds + (up + tdx) * 4096 +
                                                ((((kk * 4 + kb) << 4) + r) << 4)),
                               acc2[tdx]);
        float vals[8];
        xpose2(wscr, acc2, 0, r, kb, urow, cb, usel, vals);
        int gn = (wpxb * 32 + up + usel) * 16 + cb;
        int gm = wv * 16 + urow;
        bf16x8 o;
#pragma unroll
        for (int j = 0; j < 8; ++j) o[j] = (bf16)fmaxf(vals[j] + p.phx_b[gn + j], 0.f);
        cst16(&p.PHIX[gm * HD + gn], o);
      }
    }
    gbar(p.ARR, p.SUM, ++bs);

    // ================= Phase Q (merged: special chain -> PFLAG -> giz) ==============
    if (cls == 0) { // meanstd -> z/kld -> phiz -> set PFLAG
      const int m0 = b * 16;
      const int mat = wv & 3, half = wv >> 2;
      float* sm = (float*)(lds + 131072);
      bf16* zs = (bf16*)(lds + 152064);
      float* red = (float*)(lds + 154368);
      {
        const bf16* Arow = ((mat < 2) ? p.PT : p.ET) + (size_t)(m0 + r) * HD;
        bf16x8 af[32];
#pragma unroll
        for (int kk = 0; kk < 32; ++kk) af[kk] = *(const bf16x8*)(Arow + kk * 32 + kb * 8);
        const float* bw = mat == 0 ? p.pm_b : mat == 1 ? p.ps_b : mat == 2 ? p.em_b : p.es_b;
#pragma unroll 1
        for (int nt = 0; nt < 2; ++nt) {
          int colb = half * 32 + nt * 16;
          f32x4 acc = {};
#pragma unroll
          for (int kk = 0; kk < 32; ++kk)
            acc = mfma16(af[kk],
                         *(const bf16x8*)(p.WB + (size_t)(mat * 64 + colb + r) * 1024 +
                                          kk * 32 + kb * 8),
                         acc);
#pragma unroll
          for (int qq = 0; qq < 4; ++qq)
            sm[mat * 1024 + (kb * 4 + qq) * 64 + colb + r] = acc[qq] + bw[colb + r];
        }
      }
      __syncthreads();
      float kacc = 0.f;
      for (int e = tid; e < 1024; e += 512) {
        int row = e >> 6, col = e & 63;
        float pm = sm[row * 64 + col], ps = sm[1024 + row * 64 + col];
        float em = sm[2048 + row * 64 + col], es = sm[3072 + row * 64 + col];
        float ev = p.eps[((size_t)t * BATCH + m0 + row) * ZD + col];
        zs[row * 72 + col] = (bf16)(em + ev * __expf(0.5f * es));
        float dm = em - pm;
        kacc += 1.f + es - dm * dm - __expf(es - ps);
      }
#pragma unroll
      for (int off = 32; off; off >>= 1) kacc += __shfl_down(kacc, off, 64);
      if (lane == 0) red[wv] = kacc;
      __syncthreads(); // sm dead from here: reuse as wscr
      if (tid == 0) {
        float ss = 0.f;
        for (int i = 0; i < 8; ++i) ss += red[i];
        p.KLD[t * 8 + b] = ss;
      }
      bf16x8 afz[2];
      afz[0] = *(const bf16x8*)(zs + r * 72 + kb * 8);
      afz[1] = *(const bf16x8*)(zs + r * 72 + 32 + kb * 8);
#pragma unroll 1
      for (int jp = 0; jp < 8; jp += 2) {
        f32x4 acc2[2] = {};
#pragma unroll
        for (int tdx = 0; tdx < 2; ++tdx) {
          int u = wv * 8 + jp + tdx;
#pragma unroll
          for (int kk = 0; kk < 2; ++kk)
            acc2[tdx] = mfma16(afz[kk],
                               *(const bf16x8*)(lds + u * 2048 +
                                                ((((kk * 4 + kb) << 4) + r) << 4)),
                               acc2[tdx]);
        }
        float vals[8];
        xpose2(wscr, acc2, 0, r, kb, urow, cb, usel, vals);
        int gn = (wv * 8 + jp + usel) * 16 + cb;
        int gm = m0 + urow;
        bf16x8 o;
#pragma unroll
        for (int j = 0; j < 8; ++j) o[j] = (bf16)fmaxf(vals[j] + p.pz_b[gn + j], 0.f);
        cst16(&p.PHIZ[(size_t)cur * BH + gm * HD + gn], o);
      }
      asm volatile("s_waitcnt vmcnt(0)" ::: "memory"); // phiz at coherence point
      __syncthreads();
      if (tid == 0)
        __hip_atomic_store(p.PFLAG + (size_t)b * 32, (unsigned)(t + 1), __ATOMIC_RELAXED,
                           __HIP_MEMORY_SCOPE_AGENT);
    } else if (cls == 4 && t < SEQ - 1) { // [encx|gix]_{t+1} = phix @ [WXX|WIX]
      const bf16* Arow = p.PHIX + (size_t)(wv * 16 + r) * HD;
      f32x4 acc[4] = {};
      run_units<4>(Arow, lds, acc, r, kb);
#pragma unroll
      for (int up = 0; up < 4; up += 2) {
        float vals[8];
        xpose2(wscr, acc, up, r, kb, urow, cb, usel, vals);
        int uid = uid0 + up + usel;
        int gm = wv * 16 + urow;
        if (uid < 64) {
          int c = uid * 16 + cb;
          bf16x8 o;
#pragma unroll
          for (int j = 0; j < 8; ++j) o[j] = (bf16)(vals[j] + p.enc_b[c + j]);
          cst16(&p.ENCX[(size_t)oth * BH + gm * HD + c], o);
        } else {
          int c = (uid - 64) * 16 + cb;
          f32x4 g0, g1;
#pragma unroll
          for (int j = 0; j < 4; ++j) g0[j] = vals[j] + p.gru_bi[c + j];
#pragma unroll
          for (int j = 0; j < 4; ++j) g1[j] = vals[4 + j] + p.gru_bi[c + 4 + j];
          cst16f(&p.GIX[(size_t)oth * B3 + gm * 3072 + c], g0);
          cst16f(&p.GIX[(size_t)oth * B3 + gm * 3072 + c + 4], g1);
        }
      }
    } else if (cls == 5 && t > 0) { // dec2_{t-1} + recon + sigmoid
      const bf16* Arow = p.DECH + (size_t)(wv * 16 + r) * HD;
      f32x4 acc[4] = {};
      run_units<4>(Arow, lds, acc, r, kb);
      float racc = 0.f;
#pragma unroll
      for (int up = 0; up < 4; up += 2) {
        float vals[8];
        xpose2(wscr, acc, up, r, kb, urow, cb, usel, vals);
        int c = (uid0 + up + usel) * 16 + cb;
        int gm = wv * 16 + urow;
        size_t oi = ((size_t)(t - 1) * BATCH + gm) * XD + c;
#pragma unroll
        for (int j = 0; j < 8; ++j) {
          float l = vals[j] + p.dec2_b[c + j];
          p.out[2 + oi + j] = sigmoidf_(l);
          float spp = fmaxf(l, 0.f) + log1pf(__expf(-fabsf(l)));
          racc += spp - p.x[oi + j] * l;
        }
      }
#pragma unroll
      for (int off = 32; off; off >>= 1) racc += __shfl_down(racc, off, 64);
      if (lane == 0) p.RPART[(t - 1) * 64 + uid0 * 2 + wv] = racc;
    } else if (cls == 6) { // wait for all 8 phiz producers, then fused giz + GRU
      if (tid < 8) {
        const unsigned* f = p.PFLAG + (size_t)tid * 32;
        while (__hip_atomic_load(f, __ATOMIC_RELAXED, __HIP_MEMORY_SCOPE_AGENT) <
               (unsigned)(t + 1))
          __builtin_amdgcn_s_sleep(1);
      }
      __syncthreads();
      __builtin_amdgcn_sched_barrier(0);
      float* scR = (float*)(lds + 98304); // [2 khalf][4 mtg][3 g][16][16] f32
      const int khalf = wv >> 2, mtg = wv & 3;
#pragma unroll 1
      for (int pass = 0; pass < 2; ++pass) {
        int mt = mtg + 4 * pass;
        const bf16* Arow = p.PHIZ + (size_t)cur * BH + (size_t)(mt * 16 + r) * HD;
        bf16x8 af[16];
#pragma unroll
        for (int kk = 0; kk < 16; ++kk)
          af[kk] = *(const bf16x8*)(Arow + khalf * 512 + kk * 32 + kb * 8);
        f32x4 a3[3] = {};
#pragma unroll
        for (int kk = 0; kk < 16; ++kk) {
          bf16x8 a = af[kk];
#pragma unroll
          for (int g = 0; g < 3; ++g)
            a3[g] = mfma16(a,
                           *(const bf16x8*)(lds + g * 32768 +
                                            (((((khalf * 16 + kk) * 4 + kb) << 4) + r) << 4)),
                           a3[g]);
        }
#pragma unroll
        for (int g = 0; g < 3; ++g)
#pragma unroll
          for (int q = 0; q < 4; ++q)
            scR[khalf * 3072 + mtg * 768 + g * 256 + (kb * 4 + q) * 16 + r] = a3[g][q];
        __syncthreads();
        if (tid < 128) {
          int mtg2 = tid >> 5, row = (tid & 31) >> 1, cb2 = (tid & 1) * 8;
          int gm = (mtg2 + 4 * pass) * 16 + row;
          int c = gizj * 16 + cb2;
          int base = mtg2 * 768 + row * 16 + cb2;
          float iv[3][8], hv[3][8];
#pragma unroll
          for (int g = 0; g < 3; ++g) {
            f32x4 i0 = *(const f32x4*)(p.GIX + (size_t)cur * B3 + gm * 3072 + g * 1024 + c);
            f32x4 i1 = *(const f32x4*)(p.GIX + (size_t)cur * B3 + gm * 3072 + g * 1024 + c + 4);
            f32x4 h0 = *(const f32x4*)(p.GH + gm * 3072 + g * 1024 + c);
            f32x4 h1 = *(const f32x4*)(p.GH + gm * 3072 + g * 1024 + c + 4);
#pragma unroll
            for (int j = 0; j < 8; ++j) {
              float part = scR[base + g * 256 + j] + scR[3072 + base + g * 256 + j];
              iv[g][j] = part + ((j < 4) ? i0[j] : i1[j - 4]);
              hv[g][j] = (j < 4) ? h0[j] : h1[j - 4];
            }
          }
          f32x4 hc0 = *(const f32x4*)(p.H + gm * HD + c);
          f32x4 hc1 = *(const f32x4*)(p.H + gm * HD + c + 4);
          f32x4 hn0, hn1;
          bf16x8 o;
#pragma unroll
          for (int j = 0; j < 8; ++j) {
            float rr2 = sigmoidf_(iv[0][j] + hv[0][j]);
            float zg = sigmoidf_(iv[1][j] + hv[1][j]);
            float nn = tanhf(iv[2][j] + rr2 * hv[2][j]);
            float hvv = (j < 4) ? hc0[j] : hc1[j - 4];
            float hnew = (1.f - zg) * nn + zg * hvv;
            if (j < 4) hn0[j] = hnew; else hn1[j - 4] = hnew;
            o[j] = (bf16)hnew;
          }
          *(f32x4*)(p.H + gm * HD + c) = hn0;
          *(f32x4*)(p.H + gm * HD + c + 4) = hn1;
          cst16(&p.HB[gm * HD + c], o);
        }
        __syncthreads();
      }
    }
    gbar(p.ARR, p.SUM, ++bs);
  }
}

// ---------------- epilogue dec2 for t=255 -------------------------------------------
__global__ void dec2_last(const bf16* __restrict__ A, const bf16* __restrict__ W,
                          const float* __restrict__ x, const float* __restrict__ b2,
                          float* __restrict__ out, float* __restrict__ rpart) {
  const int lane = threadIdx.x & 63;
  const int r = lane & 15, kb = lane >> 4;
  const int w = blockIdx.x * 4 + (threadIdx.x >> 6); // 0..63
  const int m0 = (w & 7) * 16, n0 = (w >> 3) * 16;
  f32x4 acc[1][1] = {};
  const bf16* a0 = A + (size_t)(m0 + r) * HD + kb * 8;
  const bf16* b0 = W + (size_t)(n0 + r) * HD + kb * 8;
  mma_block<1, 1>(a0, 0, b0, (size_t)16 * HD, HD, acc);
  float racc = 0.f;
#pragma unroll
  for (int q = 0; q < 4; ++q) {
    int gm = m0 + kb * 4 + q, gn = n0 + r;
    float l = acc[0][0][q] + b2[gn];
    size_t oi = ((size_t)255 * BATCH + gm) * XD + gn;
    out[2 + oi] = sigmoidf_(l);
    float spp = fmaxf(l, 0.f) + log1pf(__expf(-fabsf(l)));
    racc += spp - x[oi] * l;
  }
#pragma unroll
  for (int off = 32; off; off >>= 1) racc += __shfl_down(racc, off, 64);
  if (lane == 0) rpart[255 * 64 + w] = racc;
}

__global__ void finalize_k(const float* __restrict__ rp, const float* __restrict__ kp,
                           float* __restrict__ out) {
  __shared__ float s[256];
  int tid = threadIdx.x;
  float a = 0.f;
  for (int i = tid; i < 256 * 64; i += 256) a += rp[i];
  s[tid] = a;
  __syncthreads();
  for (int off = 128; off > 0; off >>= 1) {
    if (tid < off) s[tid] += s[tid + off];
    __syncthreads();
  }
  if (tid == 0) out[0] = s[0] / (float)BATCH;
  __syncthreads();
  float bb = 0.f;
  for (int i = tid; i < 2048; i += 256) bb += kp[i];
  s[tid] = bb;
  __syncthreads();
  for (int off = 128; off > 0; off >>= 1) {
    if (tid < off) s[tid] += s[tid + off];
    __syncthreads();
  }
  if (tid == 0) out[1] = -0.5f * s[0] / (float)BATCH;
}

__global__ void sentinel_k(float* out) {
  if (threadIdx.x == 0) { out[0] = 1e9f; out[1] = 1e9f; }
}

// =====================================================================================
extern "C" void kernel_launch(void* const* d_in, const int* in_sizes, int n_in, void* d_out,
                              int out_size, void* d_ws, size_t ws_size, hipStream_t stream) {
  const float* x = (const float*)d_in[0];
  const float* eps = (const float*)d_in[1];
  const float* phi_x_W = (const float*)d_in[2];
  const float* phi_x_b = (const float*)d_in[3];
  const float* enc_W = (const float*)d_in[4];
  const float* enc_b = (const float*)d_in[5];
  const float* enc_mean_W = (const float*)d_in[6];
  const float* enc_mean_b = (const float*)d_in[7];
  const float* enc_std_W = (const float*)d_in[8];
  const float* enc_std_b = (const float*)d_in[9];
  const float* prior_W = (const float*)d_in[10];
  const float* prior_b = (const float*)d_in[11];
  const float* prior_mean_W = (const float*)d_in[12];
  const float* prior_mean_b = (const float*)d_in[13];
  const float* prior_std_W = (const float*)d_in[14];
  const float* prior_std_b = (const float*)d_in[15];
  const float* phi_z_W = (const float*)d_in[16];
  const float* phi_z_b = (const float*)d_in[17];
  const float* dec1_W = (const float*)d_in[18];
  const float* dec1_b = (const float*)d_in[19];
  const float* dec2_W = (const float*)d_in[20];
  const float* dec2_b = (const float*)d_in[21];
  const float* gru_Wi = (const float*)d_in[22];
  const float* gru_Wh = (const float*)d_in[23];
  const float* gru_bi = (const float*)d_in[24];
  const float* gru_bh = (const float*)d_in[25];
  float* out = (float*)d_out;

  char* w = (char*)d_ws;
  auto carve = [&](size_t bytes) {
    char* pp = w;
    w += (bytes + 255) & ~(size_t)255;
    return pp;
  };
  bf16* WA = (bf16*)carve((size_t)6144 * HD * 2);  // [prior;ench;gh;dhp]
  bf16* WB = (bf16*)carve((size_t)256 * HD * 2);   // [pm;ps;em;es]
  bf16* WPZ = (bf16*)carve((size_t)HD * ZD * 2);
  bf16* WIZ = (bf16*)carve((size_t)3072 * HD * 2); // gru_Wi[:,1024:]
  bf16* WIX = (bf16*)carve((size_t)3072 * HD * 2); // gru_Wi[:,:1024]
  bf16* WXX = (bf16*)carve((size_t)HD * HD * 2);   // enc_W[:,:1024]
  bf16* WPX = (bf16*)carve((size_t)HD * XD * 2);
  bf16* WDZ = (bf16*)carve((size_t)HD * HD * 2);   // dec1_W[:,:1024]
  bf16* WD2 = (bf16*)carve((size_t)XD * HD * 2);
  bf16* XBF = (bf16*)carve((size_t)MROWS * XD * 2);
  float* H = (float*)carve((size_t)BH * 4);
  bf16* HB = (bf16*)carve((size_t)BH * 2);
  bf16* PT = (bf16*)carve((size_t)BH * 2);
  bf16* ET = (bf16*)carve((size_t)BH * 2);
  float* GH = (float*)carve((size_t)B3 * 4);
  bf16* PHIX = (bf16*)carve((size_t)BH * 2);
  bf16* ENCX = (bf16*)carve((size_t)2 * BH * 2);
  bf16* PHIZ = (bf16*)carve((size_t)2 * BH * 2);
  bf16* DHP = (bf16*)carve((size_t)2 * BH * 2);
  bf16* DECH = (bf16*)carve((size_t)BH * 2);
  float* GIX = (float*)carve((size_t)2 * B3 * 4);
  float* KLD = (float*)carve((size_t)SEQ * 8 * 4);
  float* RPART = (float*)carve((size_t)SEQ * 64 * 4);
  unsigned* ARR = (unsigned*)carve((size_t)NBLK * 32 * 4);
  unsigned* SUM = (unsigned*)carve((size_t)16 * 32 * 4);
  unsigned* PFLAG = (unsigned*)carve((size_t)8 * 32 * 4);
  if ((size_t)(w - (char*)d_ws) > ws_size) {
    sentinel_k<<<1, 64, 0, stream>>>(out);
    return;
  }

  auto cvt = [&](bf16* dst, const float* src, long n, int cols, int ld, int off) {
    int grid = (int)std::min((n + 255) / 256, (long)2048);
    cvt_k<<<grid, 256, 0, stream>>>(dst, src, n, cols, ld, off);
  };
  cvt(WA, prior_W, (long)HD * HD, HD, HD, 0);
  cvt(WA + (size_t)HD * HD, enc_W, (long)HD * HD, HD, 2 * HD, HD);
  cvt(WA + (size_t)2048 * HD, gru_Wh, (long)3072 * HD, HD, HD, 0);
  cvt(WA + (size_t)5120 * HD, dec1_W, (long)HD * HD, HD, 2 * HD, HD);
  cvt(WB, prior_mean_W, (long)ZD * HD, HD, HD, 0);
  cvt(WB + (size_t)64 * HD, prior_std_W, (long)ZD * HD, HD, HD, 0);
  cvt(WB + (size_t)128 * HD, enc_mean_W, (long)ZD * HD, HD, HD, 0);
  cvt(WB + (size_t)192 * HD, enc_std_W, (long)ZD * HD, HD, HD, 0);
  cvt(WPZ, phi_z_W, (long)HD * ZD, ZD, ZD, 0);
  cvt(WIZ, gru_Wi, (long)3072 * HD, HD, 2 * HD, HD);
  cvt(WIX, gru_Wi, (long)3072 * HD, HD, 2 * HD, 0);
  cvt(WXX, enc_W, (long)HD * HD, HD, 2 * HD, 0);
  cvt(WPX, phi_x_W, (long)HD * XD, XD, XD, 0);
  cvt(WDZ, dec1_W, (long)HD * HD, HD, 2 * HD, 0);
  cvt(WD2, dec2_W, (long)XD * HD, HD, HD, 0);
  cvt(XBF, x, (long)MROWS * XD, XD, XD, 0);

  hipMemsetAsync(H, 0, (size_t)BH * 4, stream);
  hipMemsetAsync(HB, 0, (size_t)BH * 2, stream);
  hipMemsetAsync(RPART, 0, (size_t)SEQ * 64 * 4, stream);
  hipMemsetAsync(ARR, 0, (size_t)NBLK * 32 * 4, stream);
  hipMemsetAsync(SUM, 0, (size_t)16 * 32 * 4, stream);
  hipMemsetAsync(PFLAG, 0, (size_t)8 * 32 * 4, stream);

  // prologue: phi_x_0 -> encx_0, gix_0 (slot 0)
  Epi e1{PHIX, nullptr, phi_x_b, nullptr, 1, HD};
  gemm_bt<2, 2><<<32, 256, 0, stream>>>(XBF, XD, WPX, XD, BATCH, HD, XD, e1);
  Epi e2{ENCX, nullptr, enc_b, nullptr, 0, HD};
  gemm_bt<2, 2><<<32, 256, 0, stream>>>(PHIX, HD, WXX, HD, BATCH, HD, HD, e2);
  Epi e3{nullptr, GIX, gru_bi, nullptr, 0, 3072};
  gemm_bt<2, 2><<<96, 256, 0, stream>>>(PHIX, HD, WIX, HD, BATCH, 3072, HD, e3);

  LoopP lp;
  lp.WA = WA; lp.WB = WB; lp.WPZ = WPZ; lp.WIZ = WIZ; lp.WIX = WIX; lp.WXX = WXX;
  lp.WPX = WPX; lp.WDZ = WDZ; lp.WD2 = WD2; lp.XBF = XBF;
  lp.HB = HB; lp.PT = PT; lp.ET = ET; lp.PHIX = PHIX; lp.ENCX = ENCX; lp.PHIZ = PHIZ;
  lp.DHP = DHP; lp.DECH = DECH;
  lp.H = H; lp.GH = GH; lp.GIX = GIX; lp.KLD = KLD; lp.RPART = RPART; lp.out = out;
  lp.ARR = ARR; lp.SUM = SUM; lp.PFLAG = PFLAG;
  lp.eps = eps; lp.x = x;
  lp.prior_b = prior_b; lp.gru_bh = gru_bh; lp.gru_bi = gru_bi;
  lp.pm_b = prior_mean_b; lp.ps_b = prior_std_b; lp.em_b = enc_mean_b; lp.es_b = enc_std_b;
  lp.pz_b = phi_z_b; lp.phx_b = phi_x_b; lp.enc_b = enc_b; lp.dec1_b = dec1_b;
  lp.dec2_b = dec2_b;

  hipFuncSetAttribute(reinterpret_cast<const void*>(vrnn_loop),
                      hipFuncAttributeMaxDynamicSharedMemorySize, DYN_LDS);
  void* args[] = {&lp};
  hipLaunchCooperativeKernel(reinterpret_cast<const void*>(vrnn_loop), dim3(NBLK), dim3(512),
                             args, DYN_LDS, stream);

  // epilogue: dec1_255 (slot 1), dec2_255, losses
  Epi e4{DECH, nullptr, dec1_b, DHP + (size_t)1 * BH, 1, HD};
  gemm_bt<2, 2><<<32, 256, 0, stream>>>(PHIZ + (size_t)1 * BH, HD, WDZ, HD, BATCH, HD, HD, e4);
  dec2_last<<<16, 256, 0, stream>>>(DECH, WD2, x, dec2_b, out, RPART);
  finalize_k<<<1, 256, 0, stream>>>(RPART, KLD, out);
}

// Round 14
// 18359.114 us; speedup vs baseline: 1.7753x; 1.1434x over previous
//
#include <hip/hip_runtime.h>
#include <algorithm>

typedef __bf16 bf16;
typedef __bf16 bf16x8 __attribute__((ext_vector_type(8)));
typedef float f32x4 __attribute__((ext_vector_type(4)));
typedef unsigned long long u64;

// SEQ=256, B=128, XD=128, HD=1024, ZD=64
#define SEQ 256
#define BATCH 128
#define XD 128
#define HD 1024
#define ZD 64
#define MROWS (SEQ * BATCH)
#define BH (BATCH * HD)   // 131072
#define B3 (BATCH * 3072) // 393216
#define DYN_LDS 154432
#define NBLK 256

__device__ __forceinline__ f32x4 mfma16(bf16x8 a, bf16x8 b, f32x4 c) {
  return __builtin_amdgcn_mfma_f32_16x16x32_bf16(a, b, c, 0, 0, 0);
}
__device__ __forceinline__ float sigmoidf_(float x) { return 1.f / (1.f + __expf(-x)); }

// ---- 16B write-through stores (cross-block visible; proven semantics) --------------
__device__ __forceinline__ void cst16(bf16* p, bf16x8 v) {
  asm volatile("global_store_dwordx4 %0, %1, off sc0 sc1" ::"v"(p), "v"(v) : "memory");
}
__device__ __forceinline__ void cst16f(float* p, f32x4 v) {
  asm volatile("global_store_dwordx4 %0, %1, off sc0 sc1" ::"v"(p), "v"(v) : "memory");
}

// ---- flag helpers (R13-proven pattern) ---------------------------------------------
__device__ __forceinline__ void flagwait1(const unsigned* f, unsigned want) {
  while (__hip_atomic_load(f, __ATOMIC_RELAXED, __HIP_MEMORY_SCOPE_AGENT) < want)
    __builtin_amdgcn_s_sleep(1);
}

// ---- two-level tree grid barrier; agent-scope acquire fence ------------------------
__device__ __forceinline__ void gbar(unsigned* arr, unsigned* sum, unsigned serial) {
  asm volatile("s_waitcnt vmcnt(0) lgkmcnt(0)" ::: "memory");
  __syncthreads();
  const int tid = threadIdx.x;
  const int bid = blockIdx.x;
  if (tid == 0)
    __hip_atomic_store(arr + (size_t)bid * 32, serial, __ATOMIC_RELAXED,
                       __HIP_MEMORY_SCOPE_AGENT);
  if ((bid & 15) == 0 && tid < 16) {
    const unsigned* f = arr + (size_t)((bid & ~15) + tid) * 32;
    while (__hip_atomic_load(f, __ATOMIC_RELAXED, __HIP_MEMORY_SCOPE_AGENT) < serial)
      __builtin_amdgcn_s_sleep(2);
  }
  __syncthreads();
  if ((bid & 15) == 0 && tid == 0)
    __hip_atomic_store(sum + (size_t)(bid >> 4) * 32, serial, __ATOMIC_RELAXED,
                       __HIP_MEMORY_SCOPE_AGENT);
  if (tid < 16) {
    const unsigned* f = sum + (size_t)tid * 32;
    while (__hip_atomic_load(f, __ATOMIC_RELAXED, __HIP_MEMORY_SCOPE_AGENT) < serial)
      __builtin_amdgcn_s_sleep(2);
  }
  __builtin_amdgcn_fence(__ATOMIC_ACQUIRE, "agent"); // invalidate L1/L2: plain loads OK
  __syncthreads();
}

// ---------- generic mma (global A, global B) for prologue/tail kernels --------------
template <int MT, int NT>
__device__ __forceinline__ void mma_block(const bf16* __restrict__ a0, size_t aStride,
                                          const bf16* __restrict__ b0, size_t bStride,
                                          int K, f32x4 acc[MT][NT]) {
#pragma unroll 2
  for (int k = 0; k < K; k += 32) {
    bf16x8 af[MT], bfr[NT];
#pragma unroll
    for (int i = 0; i < MT; ++i) af[i] = *(const bf16x8*)(a0 + (size_t)i * aStride + k);
#pragma unroll
    for (int j = 0; j < NT; ++j) bfr[j] = *(const bf16x8*)(b0 + (size_t)j * bStride + k);
#pragma unroll
    for (int i = 0; i < MT; ++i)
#pragma unroll
      for (int j = 0; j < NT; ++j) acc[i][j] = mfma16(af[i], bfr[j], acc[i][j]);
  }
}

// ---------------- fp32 -> bf16 conversion (column slicing for concat splits) --------
__global__ void cvt_k(bf16* __restrict__ dst, const float* __restrict__ src, long n,
                      int cols, int src_ld, int col_off) {
  long i = (long)blockIdx.x * blockDim.x + threadIdx.x;
  long stride = (long)gridDim.x * blockDim.x;
  for (; i < n; i += stride) {
    long row = i / cols;
    int c = (int)(i - row * cols);
    dst[i] = (bf16)src[row * (long)src_ld + col_off + c];
  }
}

// ---------------- generic GEMM (B^T) for prologue ----------------------------------
struct Epi {
  bf16* C;
  float* Cf;
  const float* bias;
  const bf16* add;
  int relu;
  int ldc;
};

template <int MT, int NT>
__global__ void gemm_bt(const bf16* __restrict__ A, int lda, const bf16* __restrict__ B,
                        int ldb, int M, int N, int K, Epi e) {
  const int lane = threadIdx.x & 63;
  const int r = lane & 15, kb = lane >> 4;
  const int gw = blockIdx.x * (blockDim.x >> 6) + (threadIdx.x >> 6);
  const int nw = gridDim.x * (blockDim.x >> 6);
  const int ntm = M / (16 * MT), ntn = N / (16 * NT);
  for (int task = gw; task < ntm * ntn; task += nw) {
    int mt = task % ntm, nt = task / ntm;
    int m0 = mt * 16 * MT, n0 = nt * 16 * NT;
    f32x4 acc[MT][NT] = {};
    const bf16* a0 = A + (size_t)(m0 + r) * lda + kb * 8;
    const bf16* b0 = B + (size_t)(n0 + r) * ldb + kb * 8;
    mma_block<MT, NT>(a0, (size_t)16 * lda, b0, (size_t)16 * ldb, K, acc);
#pragma unroll
    for (int i = 0; i < MT; ++i)
#pragma unroll
      for (int j = 0; j < NT; ++j)
#pragma unroll
        for (int q = 0; q < 4; ++q) {
          size_t gm = (size_t)m0 + i * 16 + kb * 4 + q;
          int gn = n0 + j * 16 + r;
          float v = acc[i][j][q] + e.bias[gn];
          if (e.add) v += (float)e.add[gm * e.ldc + gn];
          if (e.relu) v = fmaxf(v, 0.f);
          if (e.Cf) e.Cf[gm * e.ldc + gn] = v;
          else e.C[gm * e.ldc + gn] = (bf16)v;
        }
  }
}

// ===================== the LDS-weight-pinned recurrence ==============================
struct LoopP {
  const bf16 *WA, *WB, *WPZ, *WIZ, *WIX, *WXX, *WPX, *WDZ, *WD2, *XBF;
  bf16 *HB, *PT, *ET, *PHIX, *ENCX, *PHIZ, *DHP, *DECH;
  float *H, *GH, *GIX, *KLD, *RPART, *out;
  unsigned *ARR, *SUM, *FLG;
  const float *eps, *x;
  const float *prior_b, *gru_bh, *gru_bi, *pm_b, *ps_b, *em_b, *es_b, *pz_b, *phx_b,
      *enc_b, *dec1_b, *dec2_b;
};

// stage 16 rows x K=1024 into k-major LDS unit: [128 kg][16 row][16B]
__device__ __forceinline__ void stage1024(char* lds, int off, const bf16* src) {
  for (int c = threadIdx.x; c < 2048; c += 512) {
    int kg = c & 127, rr = c >> 7;
    *(float4*)(lds + off + (((kg << 4) + rr) << 4)) =
        *(const float4*)(src + (size_t)rr * 1024 + kg * 8);
  }
}

template <int KK>
__device__ __forceinline__ void load_af(bf16x8* af, const bf16* A, int row, int lda, int k0,
                                        int kb) {
#pragma unroll
  for (int kk = 0; kk < KK; ++kk)
    af[kk] = *(const bf16x8*)(A + (size_t)row * lda + k0 + kk * 32 + kb * 8);
}

// NU weight units (32KB slabs); A-row via plain cached 16B loads (L1-coalesced)
template <int NU>
__device__ __forceinline__ void run_units(const bf16* Arow, const char* slab0, f32x4* acc,
                                          int r, int kb) {
  bf16x8 af[32];
#pragma unroll
  for (int kk = 0; kk < 32; ++kk) af[kk] = *(const bf16x8*)(Arow + kk * 32 + kb * 8);
#pragma unroll
  for (int u = 0; u < NU; ++u)
#pragma unroll
    for (int kk = 0; kk < 32; ++kk)
      acc[u] = mfma16(af[kk],
                      *(const bf16x8*)(slab0 + u * 32768 + ((((kk * 4 + kb) << 4) + r) << 4)),
                      acc[u]);
}

// transpose TWO 16x16 f32 tiles through per-wave padded LDS scratch.
// layout: tile stride 328 floats, row stride 20 (pad, 16B aligned).
__device__ __forceinline__ void xpose2(float* wscr, const f32x4* acc, int ua, int r, int kb,
                                       int urow, int cb, int usel, float* vals) {
#pragma unroll
  for (int tdx = 0; tdx < 2; ++tdx) {
    f32x4 a = acc[ua + tdx];
    int base = tdx * 328 + (kb * 4) * 20 + r;
#pragma unroll
    for (int q = 0; q < 4; ++q) wscr[base + q * 20] = a[q];
  }
  asm volatile("s_waitcnt lgkmcnt(0)" ::: "memory");
  __builtin_amdgcn_sched_barrier(0);
  int rb = usel * 328 + urow * 20 + cb;
#pragma unroll
  for (int j = 0; j < 8; ++j) vals[j] = wscr[rb + j];
}

// Block classes: 0 special(0-7), 1 hb(8-103), 2 dec1(104-119), 3 phix(120-121),
//                4 encx/gix(122-185), 5 dec2(186-187), 6 giz(188-251), 7 idle
// Single gbar/step; intra-step deps via FLG[b] (monotonic, posted by blocks 0-121):
//   class0 <- FLG[8..39] (PT/ET);  giz <- FLG[0..7] (phiz) + FLG[40..87] (GH);
//   class4 <- FLG[120..121] (PHIX);  class5 <- FLG[104..119] (DECH).
__global__ void __launch_bounds__(512, 1) vrnn_loop(LoopP p) {
  extern __shared__ char lds[];
  const int tid = threadIdx.x, lane = tid & 63, wv = tid >> 6;
  const int r = lane & 15, kb = lane >> 4;
  const int urow = (lane & 31) >> 1, cb = (lane & 1) * 8, usel = lane >> 5;
  const int b = blockIdx.x;
  unsigned bs = 0;

  int cls, uid0 = 0, gizj = 0, wpxb = 0;
  if (b < 8) cls = 0;
  else if (b < 104) { cls = 1; uid0 = 4 * (b - 8); }
  else if (b < 120) { cls = 2; uid0 = 4 * (b - 104); }
  else if (b < 122) { cls = 3; wpxb = b - 120; }
  else if (b < 186) { cls = 4; uid0 = 4 * (b - 122); }
  else if (b < 188) { cls = 5; uid0 = 4 * (b - 186); }
  else if (b < 252) { cls = 6; gizj = b - 188; }
  else cls = 7;

  float* wscr = (float*)(lds + 131072) + wv * 656; // classes 0-5 epilogue scratch

  // ----- one-time LDS weight staging -----
  if (cls == 0) {
    for (int c = tid; c < 8192; c += 512) { // WPZ: 64 units of 2KB (K=64)
      int kg = c & 7, rr = (c >> 3) & 15, u = c >> 7;
      *(float4*)(lds + u * 2048 + (((kg << 4) + rr) << 4)) =
          *(const float4*)(p.WPZ + (size_t)(u * 16 + rr) * 64 + kg * 8);
    }
  } else if (cls == 1) {
    for (int u = 0; u < 4; ++u) stage1024(lds, u * 32768, p.WA + (size_t)(uid0 + u) * 16 * 1024);
  } else if (cls == 2) {
    for (int u = 0; u < 4; ++u) stage1024(lds, u * 32768, p.WDZ + (size_t)(uid0 + u) * 16 * 1024);
  } else if (cls == 3) {
    for (int c = tid; c < 8192; c += 512) { // 32 WPX units of 4KB (K=128)
      int u = c >> 8, kg = c & 15, rr = (c >> 4) & 15;
      *(float4*)(lds + u * 4096 + (((kg << 4) + rr) << 4)) =
          *(const float4*)(p.WPX + (size_t)((wpxb * 32 + u) * 16 + rr) * 128 + kg * 8);
    }
  } else if (cls == 4) {
    for (int u = 0; u < 4; ++u) {
      int uid = uid0 + u;
      const bf16* src = (uid < 64) ? p.WXX + (size_t)uid * 16 * 1024
                                   : p.WIX + (size_t)(uid - 64) * 16 * 1024;
      stage1024(lds, u * 32768, src);
    }
  } else if (cls == 5) {
    for (int u = 0; u < 4; ++u) stage1024(lds, u * 32768, p.WD2 + (size_t)(uid0 + u) * 16 * 1024);
  } else if (cls == 6) {
    for (int g = 0; g < 3; ++g)
      stage1024(lds, g * 32768, p.WIZ + (size_t)(g * 1024 + gizj * 16) * 1024);
  }
  __syncthreads();

  for (int t = 0; t < SEQ; ++t) {
    const int cur = t & 1, oth = cur ^ 1;

    if (cls == 1) { // [prior|ench|gh|dhp] = h @ WA   (h = HB[oth], from giz@t-1)
      const bf16* Arow = p.HB + (size_t)oth * BH + (size_t)(wv * 16 + r) * HD;
      f32x4 acc[4] = {};
      run_units<4>(Arow, lds, acc, r, kb);
#pragma unroll
      for (int up = 0; up < 4; up += 2) {
        float vals[8];
        xpose2(wscr, acc, up, r, kb, urow, cb, usel, vals);
        int uid = uid0 + up + usel;
        int gm = wv * 16 + urow;
        if (uid < 64) {
          int gn = uid * 16 + cb;
          bf16x8 o;
#pragma unroll
          for (int j = 0; j < 8; ++j) o[j] = (bf16)fmaxf(vals[j] + p.prior_b[gn + j], 0.f);
          cst16(&p.PT[gm * HD + gn], o);
        } else if (uid < 128) {
          int c = (uid - 64) * 16 + cb;
          bf16x8 ex = *(const bf16x8*)(p.ENCX + (size_t)cur * BH + gm * HD + c);
          bf16x8 o;
#pragma unroll
          for (int j = 0; j < 8; ++j) o[j] = (bf16)fmaxf(vals[j] + (float)ex[j], 0.f);
          cst16(&p.ET[gm * HD + c], o);
        } else if (uid < 320) {
          int c = (uid - 128) * 16 + cb;
          f32x4 g0, g1;
#pragma unroll
          for (int j = 0; j < 4; ++j) g0[j] = vals[j] + p.gru_bh[c + j];
#pragma unroll
          for (int j = 0; j < 4; ++j) g1[j] = vals[4 + j] + p.gru_bh[c + 4 + j];
          cst16f(&p.GH[gm * 3072 + c], g0);
          cst16f(&p.GH[gm * 3072 + c + 4], g1);
        } else {
          int c = (uid - 320) * 16 + cb;
          bf16x8 o;
#pragma unroll
          for (int j = 0; j < 8; ++j) o[j] = (bf16)vals[j];
          cst16(&p.DHP[(size_t)cur * BH + gm * HD + c], o);
        }
      }
      asm volatile("s_waitcnt vmcnt(0)" ::: "memory");
      __syncthreads();
      if (tid == 0)
        __hip_atomic_store(p.FLG + (size_t)b * 32, (unsigned)(t + 1), __ATOMIC_RELAXED,
                           __HIP_MEMORY_SCOPE_AGENT);
    } else if (cls == 2) { // dec1_{t-1} = relu(phiz@WDZ + dhp + b)  (t-1 data: barrier-safe)
      if (t > 0) {
        const bf16* Arow = p.PHIZ + (size_t)oth * BH + (size_t)(wv * 16 + r) * HD;
        f32x4 acc[4] = {};
        run_units<4>(Arow, lds, acc, r, kb);
#pragma unroll
        for (int up = 0; up < 4; up += 2) {
          float vals[8];
          xpose2(wscr, acc, up, r, kb, urow, cb, usel, vals);
          int c = (uid0 + up + usel) * 16 + cb;
          int gm = wv * 16 + urow;
          bf16x8 dh = *(const bf16x8*)(p.DHP + (size_t)oth * BH + gm * HD + c);
          bf16x8 o;
#pragma unroll
          for (int j = 0; j < 8; ++j)
            o[j] = (bf16)fmaxf(vals[j] + (float)dh[j] + p.dec1_b[c + j], 0.f);
          cst16(&p.DECH[gm * HD + c], o);
        }
      }
      asm volatile("s_waitcnt vmcnt(0)" ::: "memory");
      __syncthreads();
      if (tid == 0)
        __hip_atomic_store(p.FLG + (size_t)b * 32, (unsigned)(t + 1), __ATOMIC_RELAXED,
                           __HIP_MEMORY_SCOPE_AGENT);
    } else if (cls == 3) { // phi_x_{t+1}
      if (t < SEQ - 1) {
        bf16x8 af2[4];
        load_af<4>(af2, p.XBF + (size_t)(t + 1) * BATCH * XD, wv * 16 + r, 128, 0, kb);
#pragma unroll 1
        for (int up = 0; up < 32; up += 2) {
          f32x4 acc2[2] = {};
#pragma unroll
          for (int tdx = 0; tdx < 2; ++tdx)
#pragma unroll
            for (int kk = 0; kk < 4; ++kk)
              acc2[tdx] = mfma16(af2[kk],
                                 *(const bf16x8*)(lds + (up + tdx) * 4096 +
                                                  ((((kk * 4 + kb) << 4) + r) << 4)),
                                 acc2[tdx]);
          float vals[8];
          xpose2(wscr, acc2, 0, r, kb, urow, cb, usel, vals);
          int gn = (wpxb * 32 + up + usel) * 16 + cb;
          int gm = wv * 16 + urow;
          bf16x8 o;
#pragma unroll
          for (int j = 0; j < 8; ++j) o[j] = (bf16)fmaxf(vals[j] + p.phx_b[gn + j], 0.f);
          cst16(&p.PHIX[gm * HD + gn], o);
        }
      }
      asm volatile("s_waitcnt vmcnt(0)" ::: "memory");
      __syncthreads();
      if (tid == 0)
        __hip_atomic_store(p.FLG + (size_t)b * 32, (unsigned)(t + 1), __ATOMIC_RELAXED,
                           __HIP_MEMORY_SCOPE_AGENT);
    } else if (cls == 0) { // wait PT/ET -> meanstd -> z/kld -> phiz -> post
      if (tid < 32) flagwait1(p.FLG + (size_t)(8 + tid) * 32, (unsigned)(t + 1));
      __syncthreads();
      __builtin_amdgcn_fence(__ATOMIC_ACQUIRE, "agent");
      __builtin_amdgcn_sched_barrier(0);
      const int m0 = b * 16;
      const int mat = wv & 3, half = wv >> 2;
      float* sm = (float*)(lds + 131072);
      bf16* zs = (bf16*)(lds + 152064);
      float* red = (float*)(lds + 154368);
      {
        const bf16* Arow = ((mat < 2) ? p.PT : p.ET) + (size_t)(m0 + r) * HD;
        bf16x8 af[32];
#pragma unroll
        for (int kk = 0; kk < 32; ++kk) af[kk] = *(const bf16x8*)(Arow + kk * 32 + kb * 8);
        const float* bw = mat == 0 ? p.pm_b : mat == 1 ? p.ps_b : mat == 2 ? p.em_b : p.es_b;
#pragma unroll 1
        for (int nt = 0; nt < 2; ++nt) {
          int colb = half * 32 + nt * 16;
          f32x4 acc = {};
#pragma unroll
          for (int kk = 0; kk < 32; ++kk)
            acc = mfma16(af[kk],
                         *(const bf16x8*)(p.WB + (size_t)(mat * 64 + colb + r) * 1024 +
                                          kk * 32 + kb * 8),
                         acc);
#pragma unroll
          for (int qq = 0; qq < 4; ++qq)
            sm[mat * 1024 + (kb * 4 + qq) * 64 + colb + r] = acc[qq] + bw[colb + r];
        }
      }
      __syncthreads();
      float kacc = 0.f;
      for (int e = tid; e < 1024; e += 512) {
        int row = e >> 6, col = e & 63;
        float pm = sm[row * 64 + col], ps = sm[1024 + row * 64 + col];
        float em = sm[2048 + row * 64 + col], es = sm[3072 + row * 64 + col];
        float ev = p.eps[((size_t)t * BATCH + m0 + row) * ZD + col];
        zs[row * 72 + col] = (bf16)(em + ev * __expf(0.5f * es));
        float dm = em - pm;
        kacc += 1.f + es - dm * dm - __expf(es - ps);
      }
#pragma unroll
      for (int off = 32; off; off >>= 1) kacc += __shfl_down(kacc, off, 64);
      if (lane == 0) red[wv] = kacc;
      __syncthreads(); // sm dead from here: reuse as wscr
      if (tid == 0) {
        float ss = 0.f;
        for (int i = 0; i < 8; ++i) ss += red[i];
        p.KLD[t * 8 + b] = ss;
      }
      bf16x8 afz[2];
      afz[0] = *(const bf16x8*)(zs + r * 72 + kb * 8);
      afz[1] = *(const bf16x8*)(zs + r * 72 + 32 + kb * 8);
#pragma unroll 1
      for (int jp = 0; jp < 8; jp += 2) {
        f32x4 acc2[2] = {};
#pragma unroll
        for (int tdx = 0; tdx < 2; ++tdx) {
          int u = wv * 8 + jp + tdx;
#pragma unroll
          for (int kk = 0; kk < 2; ++kk)
            acc2[tdx] = mfma16(afz[kk],
                               *(const bf16x8*)(lds + u * 2048 +
                                                ((((kk * 4 + kb) << 4) + r) << 4)),
                               acc2[tdx]);
        }
        float vals[8];
        xpose2(wscr, acc2, 0, r, kb, urow, cb, usel, vals);
        int gn = (wv * 8 + jp + usel) * 16 + cb;
        int gm = m0 + urow;
        bf16x8 o;
#pragma unroll
        for (int j = 0; j < 8; ++j) o[j] = (bf16)fmaxf(vals[j] + p.pz_b[gn + j], 0.f);
        cst16(&p.PHIZ[(size_t)cur * BH + gm * HD + gn], o);
      }
      asm volatile("s_waitcnt vmcnt(0)" ::: "memory");
      __syncthreads();
      if (tid == 0)
        __hip_atomic_store(p.FLG + (size_t)b * 32, (unsigned)(t + 1), __ATOMIC_RELAXED,
                           __HIP_MEMORY_SCOPE_AGENT);
    } else if (cls == 4) { // wait PHIX -> [encx|gix]_{t+1}
      if (tid < 2) flagwait1(p.FLG + (size_t)(120 + tid) * 32, (unsigned)(t + 1));
      __syncthreads();
      __builtin_amdgcn_fence(__ATOMIC_ACQUIRE, "agent");
      __builtin_amdgcn_sched_barrier(0);
      if (t < SEQ - 1) {
        const bf16* Arow = p.PHIX + (size_t)(wv * 16 + r) * HD;
        f32x4 acc[4] = {};
        run_units<4>(Arow, lds, acc, r, kb);
#pragma unroll
        for (int up = 0; up < 4; up += 2) {
          float vals[8];
          xpose2(wscr, acc, up, r, kb, urow, cb, usel, vals);
          int uid = uid0 + up + usel;
          int gm = wv * 16 + urow;
          if (uid < 64) {
            int c = uid * 16 + cb;
            bf16x8 o;
#pragma unroll
            for (int j = 0; j < 8; ++j) o[j] = (bf16)(vals[j] + p.enc_b[c + j]);
            cst16(&p.ENCX[(size_t)oth * BH + gm * HD + c], o);
          } else {
            int c = (uid - 64) * 16 + cb;
            f32x4 g0, g1;
#pragma unroll
            for (int j = 0; j < 4; ++j) g0[j] = vals[j] + p.gru_bi[c + j];
#pragma unroll
            for (int j = 0; j < 4; ++j) g1[j] = vals[4 + j] + p.gru_bi[c + 4 + j];
            cst16f(&p.GIX[(size_t)oth * B3 + gm * 3072 + c], g0);
            cst16f(&p.GIX[(size_t)oth * B3 + gm * 3072 + c + 4], g1);
          }
        }
      }
    } else if (cls == 5) { // wait DECH -> dec2_{t-1} + recon + sigmoid
      if (tid < 16) flagwait1(p.FLG + (size_t)(104 + tid) * 32, (unsigned)(t + 1));
      __syncthreads();
      __builtin_amdgcn_fence(__ATOMIC_ACQUIRE, "agent");
      __builtin_amdgcn_sched_barrier(0);
      if (t > 0) {
        const bf16* Arow = p.DECH + (size_t)(wv * 16 + r) * HD;
        f32x4 acc[4] = {};
        run_units<4>(Arow, lds, acc, r, kb);
        float racc = 0.f;
#pragma unroll
        for (int up = 0; up < 4; up += 2) {
          float vals[8];
          xpose2(wscr, acc, up, r, kb, urow, cb, usel, vals);
          int c = (uid0 + up + usel) * 16 + cb;
          int gm = wv * 16 + urow;
          size_t oi = ((size_t)(t - 1) * BATCH + gm) * XD + c;
#pragma unroll
          for (int j = 0; j < 8; ++j) {
            float l = vals[j] + p.dec2_b[c + j];
            p.out[2 + oi + j] = sigmoidf_(l);
            float spp = fmaxf(l, 0.f) + log1pf(__expf(-fabsf(l)));
            racc += spp - p.x[oi + j] * l;
          }
        }
#pragma unroll
        for (int off = 32; off; off >>= 1) racc += __shfl_down(racc, off, 64);
        if (lane == 0) p.RPART[(t - 1) * 64 + uid0 * 2 + wv] = racc;
      }
    } else if (cls == 6) { // wait phiz(8) + GH(48) -> fused giz + GRU -> HB[cur]
      if (tid < 56) {
        int idx = (tid < 48) ? (40 + tid) : (tid - 48);
        flagwait1(p.FLG + (size_t)idx * 32, (unsigned)(t + 1));
      }
      __syncthreads();
      __builtin_amdgcn_fence(__ATOMIC_ACQUIRE, "agent");
      __builtin_amdgcn_sched_barrier(0);
      float* scR = (float*)(lds + 98304); // [2 khalf][4 mtg][3 g][16][16] f32
      const int khalf = wv >> 2, mtg = wv & 3;
#pragma unroll 1
      for (int pass = 0; pass < 2; ++pass) {
        int mt = mtg + 4 * pass;
        const bf16* Arow = p.PHIZ + (size_t)cur * BH + (size_t)(mt * 16 + r) * HD;
        bf16x8 af[16];
#pragma unroll
        for (int kk = 0; kk < 16; ++kk)
          af[kk] = *(const bf16x8*)(Arow + khalf * 512 + kk * 32 + kb * 8);
        f32x4 a3[3] = {};
#pragma unroll
        for (int kk = 0; kk < 16; ++kk) {
          bf16x8 a = af[kk];
#pragma unroll
          for (int g = 0; g < 3; ++g)
            a3[g] = mfma16(a,
                           *(const bf16x8*)(lds + g * 32768 +
                                            (((((khalf * 16 + kk) * 4 + kb) << 4) + r) << 4)),
                           a3[g]);
        }
#pragma unroll
        for (int g = 0; g < 3; ++g)
#pragma unroll
          for (int q = 0; q < 4; ++q)
            scR[khalf * 3072 + mtg * 768 + g * 256 + (kb * 4 + q) * 16 + r] = a3[g][q];
        __syncthreads();
        if (tid < 128) {
          int mtg2 = tid >> 5, row = (tid & 31) >> 1, cb2 = (tid & 1) * 8;
          int gm = (mtg2 + 4 * pass) * 16 + row;
          int c = gizj * 16 + cb2;
          int base = mtg2 * 768 + row * 16 + cb2;
          float iv[3][8], hv[3][8];
#pragma unroll
          for (int g = 0; g < 3; ++g) {
            f32x4 i0 = *(const f32x4*)(p.GIX + (size_t)cur * B3 + gm * 3072 + g * 1024 + c);
            f32x4 i1 = *(const f32x4*)(p.GIX + (size_t)cur * B3 + gm * 3072 + g * 1024 + c + 4);
            f32x4 h0 = *(const f32x4*)(p.GH + gm * 3072 + g * 1024 + c);
            f32x4 h1 = *(const f32x4*)(p.GH + gm * 3072 + g * 1024 + c + 4);
#pragma unroll
            for (int j = 0; j < 8; ++j) {
              float part = scR[base + g * 256 + j] + scR[3072 + base + g * 256 + j];
              iv[g][j] = part + ((j < 4) ? i0[j] : i1[j - 4]);
              hv[g][j] = (j < 4) ? h0[j] : h1[j - 4];
            }
          }
          f32x4 hc0 = *(const f32x4*)(p.H + gm * HD + c);
          f32x4 hc1 = *(const f32x4*)(p.H + gm * HD + c + 4);
          f32x4 hn0, hn1;
          bf16x8 o;
#pragma unroll
          for (int j = 0; j < 8; ++j) {
            float rr2 = sigmoidf_(iv[0][j] + hv[0][j]);
            float zg = sigmoidf_(iv[1][j] + hv[1][j]);
            float nn = tanhf(iv[2][j] + rr2 * hv[2][j]);
            float hvv = (j < 4) ? hc0[j] : hc1[j - 4];
            float hnew = (1.f - zg) * nn + zg * hvv;
            if (j < 4) hn0[j] = hnew; else hn1[j - 4] = hnew;
            o[j] = (bf16)hnew;
          }
          *(f32x4*)(p.H + gm * HD + c) = hn0;
          *(f32x4*)(p.H + gm * HD + c + 4) = hn1;
          cst16(&p.HB[(size_t)cur * BH + gm * HD + c], o);
        }
        __syncthreads();
      }
    }
    gbar(p.ARR, p.SUM, ++bs);
  }
}

// ---------------- epilogue dec2 for t=255 -------------------------------------------
__global__ void dec2_last(const bf16* __restrict__ A, const bf16* __restrict__ W,
                          const float* __restrict__ x, const float* __restrict__ b2,
                          float* __restrict__ out, float* __restrict__ rpart) {
  const int lane = threadIdx.x & 63;
  const int r = lane & 15, kb = lane >> 4;
  const int w = blockIdx.x * 4 + (threadIdx.x >> 6); // 0..63
  const int m0 = (w & 7) * 16, n0 = (w >> 3) * 16;
  f32x4 acc[1][1] = {};
  const bf16* a0 = A + (size_t)(m0 + r) * HD + kb * 8;
  const bf16* b0 = W + (size_t)(n0 + r) * HD + kb * 8;
  mma_block<1, 1>(a0, 0, b0, (size_t)16 * HD, HD, acc);
  float racc = 0.f;
#pragma unroll
  for (int q = 0; q < 4; ++q) {
    int gm = m0 + kb * 4 + q, gn = n0 + r;
    float l = acc[0][0][q] + b2[gn];
    size_t oi = ((size_t)255 * BATCH + gm) * XD + gn;
    out[2 + oi] = sigmoidf_(l);
    float spp = fmaxf(l, 0.f) + log1pf(__expf(-fabsf(l)));
    racc += spp - x[oi] * l;
  }
#pragma unroll
  for (int off = 32; off; off >>= 1) racc += __shfl_down(racc, off, 64);
  if (lane == 0) rpart[255 * 64 + w] = racc;
}

__global__ void finalize_k(const float* __restrict__ rp, const float* __restrict__ kp,
                           float* __restrict__ out) {
  __shared__ float s[256];
  int tid = threadIdx.x;
  float a = 0.f;
  for (int i = tid; i < 256 * 64; i += 256) a += rp[i];
  s[tid] = a;
  __syncthreads();
  for (int off = 128; off > 0; off >>= 1) {
    if (tid < off) s[tid] += s[tid + off];
    __syncthreads();
  }
  if (tid == 0) out[0] = s[0] / (float)BATCH;
  __syncthreads();
  float bb = 0.f;
  for (int i = tid; i < 2048; i += 256) bb += kp[i];
  s[tid] = bb;
  __syncthreads();
  for (int off = 128; off > 0; off >>= 1) {
    if (tid < off) s[tid] += s[tid + off];
    __syncthreads();
  }
  if (tid == 0) out[1] = -0.5f * s[0] / (float)BATCH;
}

__global__ void sentinel_k(float* out) {
  if (threadIdx.x == 0) { out[0] = 1e9f; out[1] = 1e9f; }
}

// =====================================================================================
extern "C" void kernel_launch(void* const* d_in, const int* in_sizes, int n_in, void* d_out,
                              int out_size, void* d_ws, size_t ws_size, hipStream_t stream) {
  const float* x = (const float*)d_in[0];
  const float* eps = (const float*)d_in[1];
  const float* phi_x_W = (const float*)d_in[2];
  const float* phi_x_b = (const float*)d_in[3];
  const float* enc_W = (const float*)d_in[4];
  const float* enc_b = (const float*)d_in[5];
  const float* enc_mean_W = (const float*)d_in[6];
  const float* enc_mean_b = (const float*)d_in[7];
  const float* enc_std_W = (const float*)d_in[8];
  const float* enc_std_b = (const float*)d_in[9];
  const float* prior_W = (const float*)d_in[10];
  const float* prior_b = (const float*)d_in[11];
  const float* prior_mean_W = (const float*)d_in[12];
  const float* prior_mean_b = (const float*)d_in[13];
  const float* prior_std_W = (const float*)d_in[14];
  const float* prior_std_b = (const float*)d_in[15];
  const float* phi_z_W = (const float*)d_in[16];
  const float* phi_z_b = (const float*)d_in[17];
  const float* dec1_W = (const float*)d_in[18];
  const float* dec1_b = (const float*)d_in[19];
  const float* dec2_W = (const float*)d_in[20];
  const float* dec2_b = (const float*)d_in[21];
  const float* gru_Wi = (const float*)d_in[22];
  const float* gru_Wh = (const float*)d_in[23];
  const float* gru_bi = (const float*)d_in[24];
  const float* gru_bh = (const float*)d_in[25];
  float* out = (float*)d_out;

  char* w = (char*)d_ws;
  auto carve = [&](size_t bytes) {
    char* pp = w;
    w += (bytes + 255) & ~(size_t)255;
    return pp;
  };
  bf16* WA = (bf16*)carve((size_t)6144 * HD * 2);  // [prior;ench;gh;dhp]
  bf16* WB = (bf16*)carve((size_t)256 * HD * 2);   // [pm;ps;em;es]
  bf16* WPZ = (bf16*)carve((size_t)HD * ZD * 2);
  bf16* WIZ = (bf16*)carve((size_t)3072 * HD * 2); // gru_Wi[:,1024:]
  bf16* WIX = (bf16*)carve((size_t)3072 * HD * 2); // gru_Wi[:,:1024]
  bf16* WXX = (bf16*)carve((size_t)HD * HD * 2);   // enc_W[:,:1024]
  bf16* WPX = (bf16*)carve((size_t)HD * XD * 2);
  bf16* WDZ = (bf16*)carve((size_t)HD * HD * 2);   // dec1_W[:,:1024]
  bf16* WD2 = (bf16*)carve((size_t)XD * HD * 2);
  bf16* XBF = (bf16*)carve((size_t)MROWS * XD * 2);
  float* H = (float*)carve((size_t)BH * 4);
  bf16* HB = (bf16*)carve((size_t)2 * BH * 2); // parity double-buffered
  bf16* PT = (bf16*)carve((size_t)BH * 2);
  bf16* ET = (bf16*)carve((size_t)BH * 2);
  float* GH = (float*)carve((size_t)B3 * 4);
  bf16* PHIX = (bf16*)carve((size_t)BH * 2);
  bf16* ENCX = (bf16*)carve((size_t)2 * BH * 2);
  bf16* PHIZ = (bf16*)carve((size_t)2 * BH * 2);
  bf16* DHP = (bf16*)carve((size_t)2 * BH * 2);
  bf16* DECH = (bf16*)carve((size_t)BH * 2);
  float* GIX = (float*)carve((size_t)2 * B3 * 4);
  float* KLD = (float*)carve((size_t)SEQ * 8 * 4);
  float* RPART = (float*)carve((size_t)SEQ * 64 * 4);
  unsigned* ARR = (unsigned*)carve((size_t)NBLK * 32 * 4);
  unsigned* SUM = (unsigned*)carve((size_t)16 * 32 * 4);
  unsigned* FLG = (unsigned*)carve((size_t)128 * 32 * 4);
  if ((size_t)(w - (char*)d_ws) > ws_size) {
    sentinel_k<<<1, 64, 0, stream>>>(out);
    return;
  }

  auto cvt = [&](bf16* dst, const float* src, long n, int cols, int ld, int off) {
    int grid = (int)std::min((n + 255) / 256, (long)2048);
    cvt_k<<<grid, 256, 0, stream>>>(dst, src, n, cols, ld, off);
  };
  cvt(WA, prior_W, (long)HD * HD, HD, HD, 0);
  cvt(WA + (size_t)HD * HD, enc_W, (long)HD * HD, HD, 2 * HD, HD);
  cvt(WA + (size_t)2048 * HD, gru_Wh, (long)3072 * HD, HD, HD, 0);
  cvt(WA + (size_t)5120 * HD, dec1_W, (long)HD * HD, HD, 2 * HD, HD);
  cvt(WB, prior_mean_W, (long)ZD * HD, HD, HD, 0);
  cvt(WB + (size_t)64 * HD, prior_std_W, (long)ZD * HD, HD, HD, 0);
  cvt(WB + (size_t)128 * HD, enc_mean_W, (long)ZD * HD, HD, HD, 0);
  cvt(WB + (size_t)192 * HD, enc_std_W, (long)ZD * HD, HD, HD, 0);
  cvt(WPZ, phi_z_W, (long)HD * ZD, ZD, ZD, 0);
  cvt(WIZ, gru_Wi, (long)3072 * HD, HD, 2 * HD, HD);
  cvt(WIX, gru_Wi, (long)3072 * HD, HD, 2 * HD, 0);
  cvt(WXX, enc_W, (long)HD * HD, HD, 2 * HD, 0);
  cvt(WPX, phi_x_W, (long)HD * XD, XD, XD, 0);
  cvt(WDZ, dec1_W, (long)HD * HD, HD, 2 * HD, 0);
  cvt(WD2, dec2_W, (long)XD * HD, HD, HD, 0);
  cvt(XBF, x, (long)MROWS * XD, XD, XD, 0);

  hipMemsetAsync(H, 0, (size_t)BH * 4, stream);
  hipMemsetAsync(HB, 0, (size_t)2 * BH * 2, stream);
  hipMemsetAsync(RPART, 0, (size_t)SEQ * 64 * 4, stream);
  hipMemsetAsync(ARR, 0, (size_t)NBLK * 32 * 4, stream);
  hipMemsetAsync(SUM, 0, (size_t)16 * 32 * 4, stream);
  hipMemsetAsync(FLG, 0, (size_t)128 * 32 * 4, stream);

  // prologue: phi_x_0 -> encx_0, gix_0 (slot 0)
  Epi e1{PHIX, nullptr, phi_x_b, nullptr, 1, HD};
  gemm_bt<2, 2><<<32, 256, 0, stream>>>(XBF, XD, WPX, XD, BATCH, HD, XD, e1);
  Epi e2{ENCX, nullptr, enc_b, nullptr, 0, HD};
  gemm_bt<2, 2><<<32, 256, 0, stream>>>(PHIX, HD, WXX, HD, BATCH, HD, HD, e2);
  Epi e3{nullptr, GIX, gru_bi, nullptr, 0, 3072};
  gemm_bt<2, 2><<<96, 256, 0, stream>>>(PHIX, HD, WIX, HD, BATCH, 3072, HD, e3);

  LoopP lp;
  lp.WA = WA; lp.WB = WB; lp.WPZ = WPZ; lp.WIZ = WIZ; lp.WIX = WIX; lp.WXX = WXX;
  lp.WPX = WPX; lp.WDZ = WDZ; lp.WD2 = WD2; lp.XBF = XBF;
  lp.HB = HB; lp.PT = PT; lp.ET = ET; lp.PHIX = PHIX; lp.ENCX = ENCX; lp.PHIZ = PHIZ;
  lp.DHP = DHP; lp.DECH = DECH;
  lp.H = H; lp.GH = GH; lp.GIX = GIX; lp.KLD = KLD; lp.RPART = RPART; lp.out = out;
  lp.ARR = ARR; lp.SUM = SUM; lp.FLG = FLG;
  lp.eps = eps; lp.x = x;
  lp.prior_b = prior_b; lp.gru_bh = gru_bh; lp.gru_bi = gru_bi;
  lp.pm_b = prior_mean_b; lp.ps_b = prior_std_b; lp.em_b = enc_mean_b; lp.es_b = enc_std_b;
  lp.pz_b = phi_z_b; lp.phx_b = phi_x_b; lp.enc_b = enc_b; lp.dec1_b = dec1_b;
  lp.dec2_b = dec2_b;

  hipFuncSetAttribute(reinterpret_cast<const void*>(vrnn_loop),
                      hipFuncAttributeMaxDynamicSharedMemorySize, DYN_LDS);
  void* args[] = {&lp};
  hipLaunchCooperativeKernel(reinterpret_cast<const void*>(vrnn_loop), dim3(NBLK), dim3(512),
                             args, DYN_LDS, stream);

  // epilogue: dec1_255 (slot 1), dec2_255, losses
  Epi e4{DECH, nullptr, dec1_b, DHP + (size_t)1 * BH, 1, HD};
  gemm_bt<2, 2><<<32, 256, 0, stream>>>(PHIZ + (size_t)1 * BH, HD, WDZ, HD, BATCH, HD, HD, e4);
  dec2_last<<<16, 256, 0, stream>>>(DECH, WD2, x, dec2_b, out, RPART);
  finalize_k<<<1, 256, 0, stream>>>(RPART, KLD, out);
}